// Round 20
// baseline (223.756 us; speedup 1.0000x reference)
//
#include <hip/hip_runtime.h>
#include <hip/hip_bf16.h>

#define CIN 128
#define NHEAD 8
#define CHD 16
#define KVOL 27
#define NBKT_MAX 512
#define CH 4096
#define NB1 64   // bn1 partial blocks
#define NB2 256  // bn2 partial blocks

constexpr float EPS_BN = 1e-5f;
constexpr float EPS_NORM = 1e-12f;

typedef __attribute__((ext_vector_type(8))) short short8;
typedef __attribute__((ext_vector_type(4))) float f32x4;

__device__ __forceinline__ float bflo(unsigned u) {
  return __uint_as_float(u << 16);
}
__device__ __forceinline__ float bfhi(unsigned u) {
  return __uint_as_float(u & 0xffff0000u);
}
__device__ __forceinline__ unsigned pk2bf(float lo, float hi) {
  __hip_bfloat16 a = __float2bfloat16(lo), b = __float2bfloat16(hi);
  return (unsigned)*(unsigned short*)&a | ((unsigned)*(unsigned short*)&b << 16);
}

// ---------------- fuseA: bn1 partials (64) | prep (64) | chist (256) -----------
__global__ __launch_bounds__(256) void k_fuseA(
    const float* __restrict__ points, const float* __restrict__ w1,
    float* __restrict__ partials1, const float* __restrict__ pos_enc,
    const float* __restrict__ wq, const float* __restrict__ wv,
    const float* __restrict__ wo, const float* __restrict__ w3,
    __hip_bfloat16* __restrict__ pnb, __hip_bfloat16* __restrict__ wqT,
    __hip_bfloat16* __restrict__ wvT, __hip_bfloat16* __restrict__ woT,
    __hip_bfloat16* __restrict__ w3b, const int* __restrict__ q_idx,
    int* __restrict__ ccnt, int N, int M) {
  __shared__ __align__(16) char smem[2048];
  int bid = blockIdx.x;
  int t = threadIdx.x;
  if (bid < 64) {
    // ---- bn1 ----
    float(*red)[6] = (float(*)[6])smem;
    float w[9];
#pragma unroll
    for (int i = 0; i < 9; ++i) w[i] = w1[i];
    float s[3] = {0.f, 0.f, 0.f}, ss[3] = {0.f, 0.f, 0.f};
    for (int n = bid * 256 + t; n < N; n += 64 * 256) {
      float p0 = points[3 * n], p1 = points[3 * n + 1], p2 = points[3 * n + 2];
#pragma unroll
      for (int j = 0; j < 3; ++j) {
        float y = p0 * w[j] + p1 * w[3 + j] + p2 * w[6 + j];
        s[j] += y;
        ss[j] += y * y;
      }
    }
#pragma unroll
    for (int j = 0; j < 3; ++j) {
      for (int off = 32; off > 0; off >>= 1) {
        s[j] += __shfl_down(s[j], off);
        ss[j] += __shfl_down(ss[j], off);
      }
    }
    if ((t & 63) == 0) {
      int wv_ = t >> 6;
#pragma unroll
      for (int j = 0; j < 3; ++j) {
        red[wv_][j] = s[j];
        red[wv_][3 + j] = ss[j];
      }
    }
    __syncthreads();
    if (t < 6) {
      float acc = red[0][t] + red[1][t] + red[2][t] + red[3][t];
      partials1[bid * 8 + t] = acc;
    }
  } else if (bid < 128) {
    // ---- prep ----
    int g = (bid - 64) * 256 + t;
    if (g < 256) {
      int kk = g >> 3, h = g & 7;
      if (kk < KVOL) {
        const float* src = pos_enc + (kk * NHEAD + h) * CHD;
        float vals[CHD];
        float s = 0.f;
#pragma unroll
        for (int i = 0; i < CHD; ++i) {
          vals[i] = src[i];
          s += vals[i] * vals[i];
        }
        float inv = 1.f / fmaxf(sqrtf(s), EPS_NORM);
#pragma unroll
        for (int i = 0; i < CHD; ++i)
          pnb[kk * CIN + h * CHD + i] = __float2bfloat16(vals[i] * inv);
      } else {
#pragma unroll
        for (int i = 0; i < CHD; ++i)
          pnb[kk * CIN + h * CHD + i] = __float2bfloat16(0.f);
      }
    }
    if (g < CIN * CIN) {
      int k = g >> 7, c = g & 127;
      int gt = c * CIN + k;
      wqT[gt] = __float2bfloat16(wq[g]);
      wvT[gt] = __float2bfloat16(wv[g]);
      woT[gt] = __float2bfloat16(wo[g]);
      w3b[g] = __float2bfloat16(w3[g]);
    }
  } else {
    // ---- chist ----
    int* lh = (int*)smem;
    for (int b = t; b < NBKT_MAX; b += 256) lh[b] = 0;
    __syncthreads();
    for (int i = (bid - 128) * 256 + t; i < M; i += 256 * 256)
      atomicAdd(&lh[q_idx[i] >> 8], 1);
    __syncthreads();
    for (int b = t; b < NBKT_MAX; b += 256) {
      int c = lh[b];
      if (c > 0) atomicAdd(&ccnt[b], c);
    }
  }
}

// ---------------- fuseB: bn2 partials (256) | cscan (1) ------------------------
__global__ __launch_bounds__(256) void k_fuseB(
    const float* __restrict__ points, const float* __restrict__ w1,
    const float* __restrict__ g1, const float* __restrict__ b1,
    const float* __restrict__ w2, const float* __restrict__ partials1,
    float* __restrict__ partials2, const int* __restrict__ ccnt,
    int* __restrict__ sbase, int* __restrict__ bcur, int N) {
  __shared__ __align__(16) char smem[3072];
  int t = threadIdx.x;
  if (blockIdx.x < NB2) {
    // ---- bn2 ----
    float(*pa)[3] = (float(*)[3])smem;
    float w[9];
#pragma unroll
    for (int i = 0; i < 9; ++i) w[i] = w1[i];
    float st[6] = {0.f, 0.f, 0.f, 0.f, 0.f, 0.f};
    for (int b = 0; b < NB1; ++b)
#pragma unroll
      for (int j = 0; j < 6; ++j) st[j] += partials1[b * 8 + j];
    float sc1[3], sh1[3];
#pragma unroll
    for (int j = 0; j < 3; ++j) {
      float m = st[j] / (float)N;
      float var = st[3 + j] / (float)N - m * m;
      float sc = rsqrtf(var + EPS_BN) * g1[j];
      sc1[j] = sc;
      sh1[j] = b1[j] - m * sc;
    }
    int c = t & 127, half = t >> 7;
    float wc0 = w2[c], wc1 = w2[CIN + c], wc2 = w2[2 * CIN + c];
    float s = 0.f, ss = 0.f;
    for (int base = blockIdx.x * 256; base < N; base += NB2 * 256) {
      int np = min(256, N - base);
      __syncthreads();
      if (t < np) {
        int n = base + t;
        float p0 = points[3 * n], p1 = points[3 * n + 1],
              p2 = points[3 * n + 2];
        float y0 = p0 * w[0] + p1 * w[3] + p2 * w[6];
        float y1 = p0 * w[1] + p1 * w[4] + p2 * w[7];
        float y2 = p0 * w[2] + p1 * w[5] + p2 * w[8];
        pa[t][0] = fmaxf(y0 * sc1[0] + sh1[0], 0.f);
        pa[t][1] = fmaxf(y1 * sc1[1] + sh1[1], 0.f);
        pa[t][2] = fmaxf(y2 * sc1[2] + sh1[2], 0.f);
      }
      __syncthreads();
      for (int p = half; p < np; p += 2) {
        float y = pa[p][0] * wc0 + pa[p][1] * wc1 + pa[p][2] * wc2;
        s += y;
        ss += y * y;
      }
    }
    __syncthreads();
    float* red = (float*)pa;
    red[t] = s;
    red[256 + t] = ss;
    __syncthreads();
    if (t < 128) {
      partials2[blockIdx.x * CIN + t] = red[t] + red[128 + t];
      partials2[NB2 * CIN + blockIdx.x * CIN + t] =
          red[256 + t] + red[256 + 128 + t];
    }
  } else {
    // ---- cscan ----
    int* wsum = (int*)smem;
    int s0 = ccnt[2 * t], s1 = ccnt[2 * t + 1];
    int s = s0 + s1;
    int l = t & 63, w = t >> 6;
    int ss = s;
    for (int off = 1; off < 64; off <<= 1) {
      int v = __shfl_up(ss, off);
      if (l >= off) ss += v;
    }
    if (l == 63) wsum[w] = ss;
    __syncthreads();
    int wb = 0;
#pragma unroll
    for (int i = 0; i < 4; ++i)
      if (i < w) wb += wsum[i];
    int ex = wb + ss - s;
    sbase[2 * t] = ex;
    sbase[2 * t + 1] = ex + s0;
    bcur[2 * t] = ex;
    bcur[2 * t + 1] = ex + s0;
    if (t == 255) sbase[NBKT_MAX] = wb + ss;
  }
}

// ---------------- fuseC: red2 (1) | prep2 (5) | bucket1 (rest) -----------------
__global__ __launch_bounds__(256) void k_fuseC(
    const float* __restrict__ partials1, const float* __restrict__ partials2,
    float* __restrict__ stats1, float* __restrict__ stats2,
    const __hip_bfloat16* __restrict__ w3b,
    const __hip_bfloat16* __restrict__ wqT,
    const __hip_bfloat16* __restrict__ wvT, const float* __restrict__ wq,
    const float* __restrict__ wv, const float* __restrict__ b3,
    const float* __restrict__ bq, const float* __restrict__ bv,
    __hip_bfloat16* __restrict__ W3qT, __hip_bfloat16* __restrict__ W3vT,
    float* __restrict__ bqp, float* __restrict__ bvp,
    const int* __restrict__ q_idx, const int* __restrict__ k_idx,
    const int* __restrict__ kernel_idx, int* __restrict__ bcur,
    unsigned* __restrict__ stg, int M) {
  __shared__ __align__(16) char smem[22544];
  int bid = blockIdx.x;
  int t = threadIdx.x;
  if (bid == 0) {
    // ---- red2 ----
    if (t < 128) {
      float s = 0.f, ss = 0.f;
      for (int b = 0; b < NB2; ++b) {
        s += partials2[b * CIN + t];
        ss += partials2[NB2 * CIN + b * CIN + t];
      }
      stats2[t] = s;
      stats2[CIN + t] = ss;
    } else if (t < 134) {
      int j = t - 128;
      float s = 0.f;
      for (int b = 0; b < NB1; ++b) s += partials1[b * 8 + j];
      stats1[j] = s;
    }
  } else if (bid < 6) {
    // ---- prep2 ----
    int pb = bid - 1;
    if (pb == 4) {
      int c = t & 127;
      const float* wsel = (t < 128) ? wq : wv;
      float s = (t < 128) ? bq[c] : bv[c];
      for (int j = 0; j < CIN; ++j) s += b3[j] * wsel[j * CIN + c];
      if (t < 128)
        bqp[c] = s;
      else
        bvp[c] = s;
      return;
    }
    int n0 = pb * 32;
    int w = t >> 6, l = t & 63;
    int lr = l & 15, lg = l >> 4;
    int colbase = w * 32;
    f32x4 cq[2][2], cv[2][2];
#pragma unroll
    for (int mt = 0; mt < 2; ++mt)
#pragma unroll
      for (int nt = 0; nt < 2; ++nt) {
        cq[mt][nt] = {0.f, 0.f, 0.f, 0.f};
        cv[mt][nt] = {0.f, 0.f, 0.f, 0.f};
      }
#pragma unroll
    for (int kk = 0; kk < 4; ++kk) {
      short8 aA[2], bQ[2], bV[2];
#pragma unroll
      for (int mt = 0; mt < 2; ++mt)
        aA[mt] = *(const short8*)(w3b + (size_t)(n0 + mt * 16 + lr) * CIN +
                                  kk * 32 + lg * 8);
#pragma unroll
      for (int nt = 0; nt < 2; ++nt) {
        size_t off = (size_t)(colbase + nt * 16 + lr) * CIN + kk * 32 + lg * 8;
        bQ[nt] = *(const short8*)(wqT + off);
        bV[nt] = *(const short8*)(wvT + off);
      }
#pragma unroll
      for (int mt = 0; mt < 2; ++mt)
#pragma unroll
        for (int nt = 0; nt < 2; ++nt) {
          cq[mt][nt] = __builtin_amdgcn_mfma_f32_16x16x32_bf16(
              aA[mt], bQ[nt], cq[mt][nt], 0, 0, 0);
          cv[mt][nt] = __builtin_amdgcn_mfma_f32_16x16x32_bf16(
              aA[mt], bV[nt], cv[mt][nt], 0, 0, 0);
        }
    }
#pragma unroll
    for (int mt = 0; mt < 2; ++mt)
#pragma unroll
      for (int nt = 0; nt < 2; ++nt)
#pragma unroll
        for (int r = 0; r < 4; ++r) {
          int k = n0 + mt * 16 + lg * 4 + r;
          int c = colbase + nt * 16 + lr;
          W3qT[(size_t)c * CIN + k] = __float2bfloat16(cq[mt][nt][r]);
          W3vT[(size_t)c * CIN + k] = __float2bfloat16(cv[mt][nt][r]);
        }
  } else {
    // ---- bucket1 ----
    int* lhist = (int*)smem;
    int* loffs = (int*)(smem + 2048);
    int* lcur = (int*)(smem + 4096);
    int* wsum = (int*)(smem + 6144);
    unsigned* buf = (unsigned*)(smem + 6160);
    int base = (bid - 6) * CH;
    for (int b = t; b < NBKT_MAX; b += 256) lhist[b] = 0;
    __syncthreads();

    int qv_[16];
#pragma unroll
    for (int j = 0; j < 16; ++j) {
      int i = base + t + j * 256;
      int q = (i < M) ? q_idx[i] : -1;
      qv_[j] = q;
      if (q >= 0) atomicAdd(&lhist[q >> 8], 1);
    }
    __syncthreads();

    {
      int s0 = lhist[2 * t], s1 = lhist[2 * t + 1];
      int s = s0 + s1;
      int l = t & 63, w = t >> 6;
      int ss = s;
      for (int off = 1; off < 64; off <<= 1) {
        int v = __shfl_up(ss, off);
        if (l >= off) ss += v;
      }
      if (l == 63) wsum[w] = ss;
      __syncthreads();
      int wb = 0;
#pragma unroll
      for (int i = 0; i < 4; ++i)
        if (i < w) wb += wsum[i];
      int ex = wb + ss - s;
      loffs[2 * t] = ex;
      loffs[2 * t + 1] = ex + s0;
      lcur[2 * t] = ex;
      lcur[2 * t + 1] = ex + s0;
    }
    __syncthreads();

#pragma unroll
    for (int j = 0; j < 16; ++j) {
      int q = qv_[j];
      if (q >= 0) {
        int i = base + t + j * 256;
        unsigned e = (unsigned)k_idx[i] | ((unsigned)kernel_idx[i] << 17) |
                     ((unsigned)(q & 255) << 22);
        int d = atomicAdd(&lcur[q >> 8], 1);
        buf[d] = e;
      }
    }
    __syncthreads();

    for (int b = t; b < NBKT_MAX; b += 256) {
      int cntb = lhist[b];
      if (cntb > 0) {
        int g = atomicAdd(&bcur[b], cntb);
        int lo = loffs[b];
        for (int j = 0; j < cntb; ++j) stg[g + j] = buf[lo + j];
      }
    }
  }
}

// ---------------- scan1 (+bucket2a merged): counts from staging + prefix -------
__global__ __launch_bounds__(256) void k_scan1(
    const unsigned* __restrict__ stg, const int* __restrict__ sbase,
    int* __restrict__ cnt, int* __restrict__ poffs, int* __restrict__ bsum,
    int N) {
  __shared__ int lh[1024];
  __shared__ int ws_[4];
  int t = threadIdx.x;
  int b = blockIdx.x;
  for (int i = t; i < 1024; i += 256) lh[i] = 0;
  __syncthreads();
#pragma unroll
  for (int sb = 0; sb < 4; ++sb) {
    int bkt = b * 4 + sb;
    int s0 = sbase[bkt], s1 = sbase[bkt + 1];
    for (int i = s0 + t; i < s1; i += 256)
      atomicAdd(&lh[sb * 256 + (stg[i] >> 22)], 1);
  }
  __syncthreads();
  int l = t & 63, w = t >> 6;
  int base = b * 1024 + t * 4;
  int pc[4];
  int s = 0;
#pragma unroll
  for (int j = 0; j < 4; ++j) {
    int c = lh[t * 4 + j];
    if (base + j < N)
      cnt[base + j] = c;
    else
      c = 0;
    pc[j] = (c + 7) & ~7;
    s += pc[j];
  }
  int own = s;
  for (int off = 1; off < 64; off <<= 1) {
    int v = __shfl_up(s, off);
    if (l >= off) s += v;
  }
  if (l == 63) ws_[w] = s;
  __syncthreads();
  int wbase = 0;
#pragma unroll
  for (int i = 0; i < 4; ++i)
    if (i < w) wbase += ws_[i];
  int ex = wbase + s - own;
#pragma unroll
  for (int j = 0; j < 4; ++j) {
    if (base + j < N) poffs[base + j] = ex;
    ex += pc[j];
  }
  if (t == 255) bsum[b] = wbase + s;
}

__global__ __launch_bounds__(256) void k_scan2(int* __restrict__ bsum,
                                               int* __restrict__ bbase, int NB,
                                               int* __restrict__ poffsN) {
  __shared__ int ws_[4];
  int t = threadIdx.x;
  int l = t & 63, w = t >> 6;
  int s = (t < NB) ? bsum[t] : 0;
  int own = s;
  for (int off = 1; off < 64; off <<= 1) {
    int v = __shfl_up(s, off);
    if (l >= off) s += v;
  }
  if (l == 63) ws_[w] = s;
  __syncthreads();
  int wbase = 0;
#pragma unroll
  for (int i = 0; i < 4; ++i)
    if (i < w) wbase += ws_[i];
  if (t < NB) bbase[t] = wbase + s - own;
  if (t == 255) *poffsN = wbase + s;
}

__global__ __launch_bounds__(256) void k_scan3(const int* __restrict__ cnt,
                                               int* __restrict__ poffs,
                                               const int* __restrict__ bbase,
                                               unsigned* __restrict__ recs,
                                               int N) {
  int t = threadIdx.x;
  int base = blockIdx.x * 1024 + t * 4;
  int bb = bbase[blockIdx.x];
#pragma unroll
  for (int j = 0; j < 4; ++j) {
    int i = base + j;
    if (i >= N) break;
    int o = poffs[i] + bb;
    poffs[i] = o;
    int c = cnt[i];
    int pcend = o + ((c + 7) & ~7);
    for (int p = o + c; p < pcend; ++p) recs[p] = 27u << 17;
  }
}

// ---------------- fused: bucket2b (NBKT blocks) | qv (rest) --------------------
__global__ __launch_bounds__(256) void k_qv_b2b(
    const unsigned* __restrict__ stg, const int* __restrict__ sbase,
    const int* __restrict__ poffs, unsigned* __restrict__ recs, int NBKT,
    const float* __restrict__ points, const float* __restrict__ feats,
    const float* __restrict__ w1, const float* __restrict__ g1,
    const float* __restrict__ b1, const float* __restrict__ w2,
    const float* __restrict__ g2, const float* __restrict__ b2,
    const __hip_bfloat16* __restrict__ wqT,
    const __hip_bfloat16* __restrict__ wvT,
    const __hip_bfloat16* __restrict__ W3qT,
    const __hip_bfloat16* __restrict__ W3vT, const float* __restrict__ bqp,
    const float* __restrict__ bvp, const float* __restrict__ stats1,
    const float* __restrict__ stats2, __hip_bfloat16* __restrict__ qnout,
    __hip_bfloat16* __restrict__ vout, int N) {
  __shared__ __align__(16) char smem[17792];
  int t = threadIdx.x;
  if ((int)blockIdx.x < NBKT) {
    // ---- bucket2b ----
    int* qcur = (int*)smem;
    int b = blockIdx.x;
    int qbase = b << 8;
    int q = qbase + t;
    qcur[t] = (q < N) ? poffs[q] : 0;
    __syncthreads();
    int start = sbase[b];
    int bcnt = sbase[b + 1] - start;
    for (int i = t; i < bcnt; i += 256) {
      unsigned e = stg[start + i];
      int ql = e >> 22;
      unsigned rec = e & 0x3FFFFFu;
      int pos = atomicAdd(&qcur[ql], 1);
      recs[pos] = rec;
    }
    return;
  }
  // ---- qv ----
  float(*h0s)[3] = (float(*)[3])smem;                                // 384 B
  __hip_bfloat16(*h1s)[136] = (__hip_bfloat16(*)[136])(smem + 384);  // 8704 B
  __hip_bfloat16(*fs)[136] = (__hip_bfloat16(*)[136])(smem + 9088);  // 8704 B

  int n0 = ((int)blockIdx.x - NBKT) * 32;

  int frow = t >> 3, fpart = t & 7;
  int fn = n0 + frow;
  float4 f0 = {0.f, 0.f, 0.f, 0.f}, f1 = f0, f2 = f0, f3 = f0;
  if (fn < N) {
    const float4* src = (const float4*)(feats + (size_t)fn * CIN + fpart * 16);
    f0 = src[0];
    f1 = src[1];
    f2 = src[2];
    f3 = src[3];
  }

  if (t < 32) {
    int n = n0 + t;
    float p0 = 0.f, p1 = 0.f, p2 = 0.f;
    if (n < N) {
      p0 = points[3 * n];
      p1 = points[3 * n + 1];
      p2 = points[3 * n + 2];
    }
#pragma unroll
    for (int j = 0; j < 3; ++j) {
      float m = stats1[j] / (float)N;
      float var = stats1[3 + j] / (float)N - m * m;
      float sc = rsqrtf(var + EPS_BN) * g1[j];
      float sh = b1[j] - m * sc;
      float y = p0 * w1[j] + p1 * w1[3 + j] + p2 * w1[6 + j];
      h0s[t][j] = fmaxf(y * sc + sh, 0.f);
    }
  }

  {
    unsigned u[8];
    u[0] = pk2bf(f0.x, f0.y);
    u[1] = pk2bf(f0.z, f0.w);
    u[2] = pk2bf(f1.x, f1.y);
    u[3] = pk2bf(f1.z, f1.w);
    u[4] = pk2bf(f2.x, f2.y);
    u[5] = pk2bf(f2.z, f2.w);
    u[6] = pk2bf(f3.x, f3.y);
    u[7] = pk2bf(f3.z, f3.w);
    unsigned* dst = (unsigned*)((char*)&fs[frow][0] + fpart * 32);
#pragma unroll
    for (int i = 0; i < 8; ++i) dst[i] = u[i];
  }
  __syncthreads();

  {
    int c = t & 127, half = t >> 7;
    float m2 = stats2[c] / (float)N;
    float v2 = stats2[CIN + c] / (float)N - m2 * m2;
    float sc2 = rsqrtf(v2 + EPS_BN) * g2[c];
    float sh2 = b2[c] - m2 * sc2;
    float wc0 = w2[c], wc1 = w2[CIN + c], wc2 = w2[2 * CIN + c];
#pragma unroll
    for (int i = 0; i < 16; ++i) {
      int p = i * 2 + half;
      float y = h0s[p][0] * wc0 + h0s[p][1] * wc1 + h0s[p][2] * wc2;
      h1s[p][c] = __float2bfloat16(fmaxf(y * sc2 + sh2, 0.f));
    }
  }
  __syncthreads();

  int w = t >> 6, l = t & 63;
  int lr = l & 15, lg = l >> 4;
  int colbase = w * 32;

  f32x4 aq[2][2], av[2][2];
#pragma unroll
  for (int nt = 0; nt < 2; ++nt) {
    float bqc = bqp[colbase + nt * 16 + lr];
    float bvc = bvp[colbase + nt * 16 + lr];
#pragma unroll
    for (int mt = 0; mt < 2; ++mt) {
      aq[mt][nt] = {bqc, bqc, bqc, bqc};
      av[mt][nt] = {bvc, bvc, bvc, bvc};
    }
  }
#pragma unroll
  for (int kk = 0; kk < 4; ++kk) {
    short8 aF[2], aH[2];
#pragma unroll
    for (int mt = 0; mt < 2; ++mt) {
      aF[mt] = *(const short8*)((const char*)fs + (mt * 16 + lr) * 272 +
                                (kk * 32 + lg * 8) * 2);
      aH[mt] = *(const short8*)((const char*)h1s + (mt * 16 + lr) * 272 +
                                (kk * 32 + lg * 8) * 2);
    }
    short8 bQf[2], bQh[2], bVf[2], bVh[2];
#pragma unroll
    for (int nt = 0; nt < 2; ++nt) {
      size_t off =
          ((size_t)(colbase + nt * 16 + lr) * CIN + kk * 32 + lg * 8) * 2;
      bQf[nt] = *(const short8*)((const char*)wqT + off);
      bQh[nt] = *(const short8*)((const char*)W3qT + off);
      bVf[nt] = *(const short8*)((const char*)wvT + off);
      bVh[nt] = *(const short8*)((const char*)W3vT + off);
    }
#pragma unroll
    for (int mt = 0; mt < 2; ++mt)
#pragma unroll
      for (int nt = 0; nt < 2; ++nt) {
        aq[mt][nt] = __builtin_amdgcn_mfma_f32_16x16x32_bf16(aF[mt], bQf[nt],
                                                             aq[mt][nt], 0, 0, 0);
        aq[mt][nt] = __builtin_amdgcn_mfma_f32_16x16x32_bf16(aH[mt], bQh[nt],
                                                             aq[mt][nt], 0, 0, 0);
        av[mt][nt] = __builtin_amdgcn_mfma_f32_16x16x32_bf16(aF[mt], bVf[nt],
                                                             av[mt][nt], 0, 0, 0);
        av[mt][nt] = __builtin_amdgcn_mfma_f32_16x16x32_bf16(aH[mt], bVh[nt],
                                                             av[mt][nt], 0, 0, 0);
      }
  }
  __syncthreads();

#pragma unroll
  for (int mt = 0; mt < 2; ++mt)
#pragma unroll
    for (int nt = 0; nt < 2; ++nt)
#pragma unroll
      for (int r = 0; r < 4; ++r) {
        float q = aq[mt][nt][r];
        float s = q * q;
        s += __shfl_xor(s, 1);
        s += __shfl_xor(s, 2);
        s += __shfl_xor(s, 4);
        s += __shfl_xor(s, 8);
        float inv = rsqrtf(fmaxf(s, EPS_NORM * EPS_NORM));
        int row = mt * 16 + lg * 4 + r;
        int col = colbase + nt * 16 + lr;
        fs[row][col] = __float2bfloat16(q * inv);
        h1s[row][col] = __float2bfloat16(av[mt][nt][r]);
      }
  __syncthreads();

  {
    int row = t >> 3, part = t & 7;
    int n = n0 + row;
    if (n < N) {
      const char* srcq = (const char*)&fs[row][0] + part * 32;
      char* dstq = (char*)qnout + (size_t)n * 256 + part * 32;
      *(uint4*)dstq = *(const uint4*)srcq;
      *(uint4*)(dstq + 16) = *(const uint4*)(srcq + 16);
      const char* srcv = (const char*)&h1s[row][0] + part * 32;
      char* dstv = (char*)vout + (size_t)n * 256 + part * 32;
      *(uint4*)dstv = *(const uint4*)srcv;
      *(uint4*)(dstv + 16) = *(const uint4*)(srcv + 16);
    }
  }
}

// ---------------- gather + in-block dots (f32, h-major) + out projection -------
__global__ __launch_bounds__(512) void k_gather_out(
    const unsigned* __restrict__ recs, const int* __restrict__ poffs,
    const __hip_bfloat16* __restrict__ qn, const __hip_bfloat16* __restrict__ v,
    const __hip_bfloat16* __restrict__ pnb,
    const __hip_bfloat16* __restrict__ woT, const float* __restrict__ bo,
    float* __restrict__ out, int N) {
  __shared__ __hip_bfloat16 accs[32][136];
  __shared__ float dotlds[32][224];  // [n-local][h*28 + kk], kk<28
  int t = threadIdx.x;
  int w = t >> 6, l = t & 63;
  int h = l >> 3;
  int n0 = blockIdx.x * 32;
  const char* vbase = (const char*)v + 4 * l;

  {
    int row = t >> 4, part = t & 15;
    int n = n0 + row;
    uint4 val = {0u, 0u, 0u, 0u};
    if (n < N)
      val = *(const uint4*)((const char*)qn + (size_t)n * 256 + part * 16);
    *(uint4*)((char*)&accs[row][0] + part * 16) = val;
  }
  __syncthreads();

  {
    int lr = l & 15, lg = l >> 4;
    int rg = w & 1;
    const short8 zero8 = {0, 0, 0, 0, 0, 0, 0, 0};
#pragma unroll
    for (int hh = 0; hh < 2; ++hh) {
      int hx = (w >> 1) * 2 + hh;
      short8 aA = zero8, bB0 = zero8, bB1 = zero8;
      if (lg < 2) {
        aA = *(const short8*)((const char*)&accs[rg * 16 + lr][0] +
                              (hx * CHD + lg * 8) * 2);
        bB0 = *(const short8*)(pnb + lr * CIN + hx * CHD + lg * 8);
        bB1 = *(const short8*)(pnb + (16 + lr) * CIN + hx * CHD + lg * 8);
      }
      f32x4 c0 = {0.f, 0.f, 0.f, 0.f}, c1 = {0.f, 0.f, 0.f, 0.f};
      c0 = __builtin_amdgcn_mfma_f32_16x16x32_bf16(aA, bB0, c0, 0, 0, 0);
      c1 = __builtin_amdgcn_mfma_f32_16x16x32_bf16(aA, bB1, c1, 0, 0, 0);
#pragma unroll
      for (int r = 0; r < 4; ++r) {
        int row = rg * 16 + lg * 4 + r;
        dotlds[row][hx * 28 + lr] = c0[r];
        if (lr < 12) dotlds[row][hx * 28 + 16 + lr] = c1[r];
      }
    }
  }
  __syncthreads();

  int hb = h * 28;
#pragma unroll 1
  for (int j = 0; j < 4; ++j) {
    int nl = w * 4 + j;
    int n = n0 + nl;
    float ax = 0.f, ay = 0.f;
    if (n < N) {
      const float* dptr = &dotlds[nl][0];
      int beg = poffs[n], end = poffs[n + 1];
      for (int idx = beg; idx < end; idx += 8) {
        unsigned r0 = recs[idx + 0], r1 = recs[idx + 1], r2 = recs[idx + 2],
                 r3 = recs[idx + 3], r4 = recs[idx + 4], r5 = recs[idx + 5],
                 r6 = recs[idx + 6], r7 = recs[idx + 7];
        unsigned v0 = *(const unsigned*)(vbase + (size_t)(r0 & 0x1FFFF) * 256);
        unsigned v1 = *(const unsigned*)(vbase + (size_t)(r1 & 0x1FFFF) * 256);
        unsigned v2 = *(const unsigned*)(vbase + (size_t)(r2 & 0x1FFFF) * 256);
        unsigned v3 = *(const unsigned*)(vbase + (size_t)(r3 & 0x1FFFF) * 256);
        unsigned v4 = *(const unsigned*)(vbase + (size_t)(r4 & 0x1FFFF) * 256);
        unsigned v5 = *(const unsigned*)(vbase + (size_t)(r5 & 0x1FFFF) * 256);
        unsigned v6 = *(const unsigned*)(vbase + (size_t)(r6 & 0x1FFFF) * 256);
        unsigned v7 = *(const unsigned*)(vbase + (size_t)(r7 & 0x1FFFF) * 256);
        float a0 = dptr[hb + (r0 >> 17)];
        float a1 = dptr[hb + (r1 >> 17)];
        float a2 = dptr[hb + (r2 >> 17)];
        float a3 = dptr[hb + (r3 >> 17)];
        float a4 = dptr[hb + (r4 >> 17)];
        float a5 = dptr[hb + (r5 >> 17)];
        float a6 = dptr[hb + (r6 >> 17)];
        float a7 = dptr[hb + (r7 >> 17)];
        ax += a0 * bflo(v0);
        ay += a0 * bfhi(v0);
        ax += a1 * bflo(v1);
        ay += a1 * bfhi(v1);
        ax += a2 * bflo(v2);
        ay += a2 * bfhi(v2);
        ax += a3 * bflo(v3);
        ay += a3 * bfhi(v3);
        ax += a4 * bflo(v4);
        ay += a4 * bfhi(v4);
        ax += a5 * bflo(v5);
        ay += a5 * bfhi(v5);
        ax += a6 * bflo(v6);
        ay += a6 * bfhi(v6);
        ax += a7 * bflo(v7);
        ay += a7 * bfhi(v7);
      }
    }
    __hip_bfloat16 bx = __float2bfloat16(ax), by = __float2bfloat16(ay);
    unsigned pk = (unsigned)*(unsigned short*)&bx |
                  ((unsigned)*(unsigned short*)&by << 16);
    ((unsigned*)((char*)accs + nl * 272))[l] = pk;
  }
  __syncthreads();

  int lr = l & 15, lg = l >> 4;
  int colb = w * 16;
  float bc = bo[colb + lr];
  f32x4 acc0 = {bc, bc, bc, bc}, acc1 = {bc, bc, bc, bc};
#pragma unroll
  for (int kk = 0; kk < 4; ++kk) {
    short8 aA0 = *(const short8*)((const char*)accs + lr * 272 +
                                  (kk * 32 + lg * 8) * 2);
    short8 aA1 = *(const short8*)((const char*)accs + (16 + lr) * 272 +
                                  (kk * 32 + lg * 8) * 2);
    short8 bB = *(const short8*)(woT + (size_t)(colb + lr) * CIN + kk * 32 +
                                 lg * 8);
    acc0 = __builtin_amdgcn_mfma_f32_16x16x32_bf16(aA0, bB, acc0, 0, 0, 0);
    acc1 = __builtin_amdgcn_mfma_f32_16x16x32_bf16(aA1, bB, acc1, 0, 0, 0);
  }
#pragma unroll
  for (int r = 0; r < 4; ++r) {
    int nr0 = n0 + lg * 4 + r;
    int nr1 = nr0 + 16;
    if (nr0 < N) out[(size_t)nr0 * CIN + colb + lr] = acc0[r];
    if (nr1 < N) out[(size_t)nr1 * CIN + colb + lr] = acc1[r];
  }
}

// ---------------- launch -------------------------------------------------------
extern "C" void kernel_launch(void* const* d_in, const int* in_sizes, int n_in,
                              void* d_out, int out_size, void* d_ws,
                              size_t ws_size, hipStream_t stream) {
  const float* points = (const float*)d_in[0];
  const float* feats = (const float*)d_in[1];
  const int* k_idx = (const int*)d_in[2];
  const int* q_idx = (const int*)d_in[3];
  const int* kernel_idx = (const int*)d_in[4];
  const float* w1 = (const float*)d_in[5];
  const float* g1 = (const float*)d_in[6];
  const float* b1 = (const float*)d_in[7];
  const float* w2 = (const float*)d_in[8];
  const float* g2 = (const float*)d_in[9];
  const float* b2 = (const float*)d_in[10];
  const float* w3 = (const float*)d_in[11];
  const float* b3 = (const float*)d_in[12];
  const float* wq = (const float*)d_in[13];
  const float* bq = (const float*)d_in[14];
  const float* wv = (const float*)d_in[15];
  const float* bv = (const float*)d_in[16];
  const float* wo = (const float*)d_in[17];
  const float* bo = (const float*)d_in[18];
  const float* pos_enc = (const float*)d_in[19];

  int N = in_sizes[0] / 3;
  int M = in_sizes[2];
  int NB = (N + 1023) / 1024;  // <= 256
  int NBKT = (N + 255) >> 8;   // <= 512
  int Np = (N + 4) & ~3;
  int NB1C = (M + CH - 1) / CH;

  float* ws = (float*)d_ws;
  float* stats1 = ws;                                 // 8
  float* stats2 = ws + 8;                             // 256 (ends 264)
  __hip_bfloat16* pnb = (__hip_bfloat16*)(ws + 264);  // 32*128 bf16 (ends 2312)
  float* bqp = ws + 2312;                             // 128
  float* bvp = ws + 2440;                             // 128 (ends 2568)
  int* cnt = (int*)(ws + 4096);                       // Np
  int* poffs = cnt + Np;                              // Np (N+1 used)
  int* bsum = poffs + Np;                             // 512
  int* bbase = bsum + 512;                            // 512
  int* bcur = bbase + 512;                            // 512
  int* ccnt = bcur + 512;                             // 512
  int* sbase = ccnt + 512;                            // 520 (513 used)
  unsigned* recs = (unsigned*)(sbase + 520);          // recn (padded)
  size_t recn = ((size_t)M + 8 * (size_t)N + 7) & ~(size_t)7;
  unsigned* stg = recs + recn;                          // M
  __hip_bfloat16* qnb = (__hip_bfloat16*)(stg + M);     // N*128
  __hip_bfloat16* vb = qnb + (size_t)N * CIN;           // N*128
  __hip_bfloat16* wqT = vb + (size_t)N * CIN;
  __hip_bfloat16* wvT = wqT + CIN * CIN;
  __hip_bfloat16* woT = wvT + CIN * CIN;
  __hip_bfloat16* W3qT = woT + CIN * CIN;
  __hip_bfloat16* W3vT = W3qT + CIN * CIN;
  __hip_bfloat16* w3b = W3vT + CIN * CIN;
  float* partials1 = (float*)(w3b + CIN * CIN);  // NB1*8
  float* partials2 = partials1 + NB1 * 8;        // 2*NB2*128
  float* outf = (float*)d_out;

  hipMemsetAsync(ccnt, 0, NBKT_MAX * sizeof(int), stream);

  k_fuseA<<<384, 256, 0, stream>>>(points, w1, partials1, pos_enc, wq, wv, wo,
                                   w3, pnb, wqT, wvT, woT, w3b, q_idx, ccnt, N,
                                   M);
  k_fuseB<<<NB2 + 1, 256, 0, stream>>>(points, w1, g1, b1, w2, partials1,
                                       partials2, ccnt, sbase, bcur, N);
  k_fuseC<<<6 + NB1C, 256, 0, stream>>>(partials1, partials2, stats1, stats2,
                                        w3b, wqT, wvT, wq, wv, b3, bq, bv, W3qT,
                                        W3vT, bqp, bvp, q_idx, k_idx,
                                        kernel_idx, bcur, stg, M);
  k_scan1<<<NB, 256, 0, stream>>>(stg, sbase, cnt, poffs, bsum, N);
  k_scan2<<<1, 256, 0, stream>>>(bsum, bbase, NB, poffs + N);
  k_scan3<<<NB, 256, 0, stream>>>(cnt, poffs, bbase, recs, N);
  k_qv_b2b<<<NBKT + (N + 31) / 32, 256, 0, stream>>>(
      stg, sbase, poffs, recs, NBKT, points, feats, w1, g1, b1, w2, g2, b2, wqT,
      wvT, W3qT, W3vT, bqp, bvp, stats1, stats2, qnb, vb, N);
  k_gather_out<<<(N + 31) / 32, 512, 0, stream>>>(recs, poffs, qnb, vb, pnb,
                                                  woT, bo, outf, N);
}

// Round 21
// 223.371 us; speedup vs baseline: 1.0017x; 1.0017x over previous
//
#include <hip/hip_runtime.h>
#include <hip/hip_bf16.h>

#define CIN 128
#define NHEAD 8
#define CHD 16
#define KVOL 27
#define NBKT_MAX 512
#define CH 4096
#define NB1 64   // bn1 partial blocks
#define NB2 256  // bn2 partial blocks

constexpr float EPS_BN = 1e-5f;
constexpr float EPS_NORM = 1e-12f;

typedef __attribute__((ext_vector_type(8))) short short8;
typedef __attribute__((ext_vector_type(4))) float f32x4;

__device__ __forceinline__ float bflo(unsigned u) {
  return __uint_as_float(u << 16);
}
__device__ __forceinline__ float bfhi(unsigned u) {
  return __uint_as_float(u & 0xffff0000u);
}
__device__ __forceinline__ unsigned pk2bf(float lo, float hi) {
  __hip_bfloat16 a = __float2bfloat16(lo), b = __float2bfloat16(hi);
  return (unsigned)*(unsigned short*)&a | ((unsigned)*(unsigned short*)&b << 16);
}

// ---------------- fuseA: bn1 partials (64) | prep (64) | chist (256) -----------
__global__ __launch_bounds__(256) void k_fuseA(
    const float* __restrict__ points, const float* __restrict__ w1,
    float* __restrict__ partials1, const float* __restrict__ pos_enc,
    const float* __restrict__ wq, const float* __restrict__ wv,
    const float* __restrict__ wo, const float* __restrict__ w3,
    __hip_bfloat16* __restrict__ pnb, __hip_bfloat16* __restrict__ wqT,
    __hip_bfloat16* __restrict__ wvT, __hip_bfloat16* __restrict__ woT,
    __hip_bfloat16* __restrict__ w3b, const int* __restrict__ q_idx,
    int* __restrict__ ccnt, int N, int M) {
  __shared__ __align__(16) char smem[2048];
  int bid = blockIdx.x;
  int t = threadIdx.x;
  if (bid < 64) {
    // ---- bn1 ----
    float(*red)[6] = (float(*)[6])smem;
    float w[9];
#pragma unroll
    for (int i = 0; i < 9; ++i) w[i] = w1[i];
    float s[3] = {0.f, 0.f, 0.f}, ss[3] = {0.f, 0.f, 0.f};
    for (int n = bid * 256 + t; n < N; n += 64 * 256) {
      float p0 = points[3 * n], p1 = points[3 * n + 1], p2 = points[3 * n + 2];
#pragma unroll
      for (int j = 0; j < 3; ++j) {
        float y = p0 * w[j] + p1 * w[3 + j] + p2 * w[6 + j];
        s[j] += y;
        ss[j] += y * y;
      }
    }
#pragma unroll
    for (int j = 0; j < 3; ++j) {
      for (int off = 32; off > 0; off >>= 1) {
        s[j] += __shfl_down(s[j], off);
        ss[j] += __shfl_down(ss[j], off);
      }
    }
    if ((t & 63) == 0) {
      int wv_ = t >> 6;
#pragma unroll
      for (int j = 0; j < 3; ++j) {
        red[wv_][j] = s[j];
        red[wv_][3 + j] = ss[j];
      }
    }
    __syncthreads();
    if (t < 6) {
      float acc = red[0][t] + red[1][t] + red[2][t] + red[3][t];
      partials1[bid * 8 + t] = acc;
    }
  } else if (bid < 128) {
    // ---- prep ----
    int g = (bid - 64) * 256 + t;
    if (g < 256) {
      int kk = g >> 3, h = g & 7;
      if (kk < KVOL) {
        const float* src = pos_enc + (kk * NHEAD + h) * CHD;
        float vals[CHD];
        float s = 0.f;
#pragma unroll
        for (int i = 0; i < CHD; ++i) {
          vals[i] = src[i];
          s += vals[i] * vals[i];
        }
        float inv = 1.f / fmaxf(sqrtf(s), EPS_NORM);
#pragma unroll
        for (int i = 0; i < CHD; ++i)
          pnb[kk * CIN + h * CHD + i] = __float2bfloat16(vals[i] * inv);
      } else {
#pragma unroll
        for (int i = 0; i < CHD; ++i)
          pnb[kk * CIN + h * CHD + i] = __float2bfloat16(0.f);
      }
    }
    if (g < CIN * CIN) {
      int k = g >> 7, c = g & 127;
      int gt = c * CIN + k;
      wqT[gt] = __float2bfloat16(wq[g]);
      wvT[gt] = __float2bfloat16(wv[g]);
      woT[gt] = __float2bfloat16(wo[g]);
      w3b[g] = __float2bfloat16(w3[g]);
    }
  } else {
    // ---- chist ----
    int* lh = (int*)smem;
    for (int b = t; b < NBKT_MAX; b += 256) lh[b] = 0;
    __syncthreads();
    for (int i = (bid - 128) * 256 + t; i < M; i += 256 * 256)
      atomicAdd(&lh[q_idx[i] >> 8], 1);
    __syncthreads();
    for (int b = t; b < NBKT_MAX; b += 256) {
      int c = lh[b];
      if (c > 0) atomicAdd(&ccnt[b], c);
    }
  }
}

// ---------------- fuseB: bn2 partials (256) | cscan (1) ------------------------
__global__ __launch_bounds__(256) void k_fuseB(
    const float* __restrict__ points, const float* __restrict__ w1,
    const float* __restrict__ g1, const float* __restrict__ b1,
    const float* __restrict__ w2, const float* __restrict__ partials1,
    float* __restrict__ partials2, const int* __restrict__ ccnt,
    int* __restrict__ sbase, int* __restrict__ bcur, int N) {
  __shared__ __align__(16) char smem[3072];
  int t = threadIdx.x;
  if (blockIdx.x < NB2) {
    // ---- bn2 ----
    float(*pa)[3] = (float(*)[3])smem;
    float w[9];
#pragma unroll
    for (int i = 0; i < 9; ++i) w[i] = w1[i];
    float st[6] = {0.f, 0.f, 0.f, 0.f, 0.f, 0.f};
    for (int b = 0; b < NB1; ++b)
#pragma unroll
      for (int j = 0; j < 6; ++j) st[j] += partials1[b * 8 + j];
    float sc1[3], sh1[3];
#pragma unroll
    for (int j = 0; j < 3; ++j) {
      float m = st[j] / (float)N;
      float var = st[3 + j] / (float)N - m * m;
      float sc = rsqrtf(var + EPS_BN) * g1[j];
      sc1[j] = sc;
      sh1[j] = b1[j] - m * sc;
    }
    int c = t & 127, half = t >> 7;
    float wc0 = w2[c], wc1 = w2[CIN + c], wc2 = w2[2 * CIN + c];
    float s = 0.f, ss = 0.f;
    for (int base = blockIdx.x * 256; base < N; base += NB2 * 256) {
      int np = min(256, N - base);
      __syncthreads();
      if (t < np) {
        int n = base + t;
        float p0 = points[3 * n], p1 = points[3 * n + 1],
              p2 = points[3 * n + 2];
        float y0 = p0 * w[0] + p1 * w[3] + p2 * w[6];
        float y1 = p0 * w[1] + p1 * w[4] + p2 * w[7];
        float y2 = p0 * w[2] + p1 * w[5] + p2 * w[8];
        pa[t][0] = fmaxf(y0 * sc1[0] + sh1[0], 0.f);
        pa[t][1] = fmaxf(y1 * sc1[1] + sh1[1], 0.f);
        pa[t][2] = fmaxf(y2 * sc1[2] + sh1[2], 0.f);
      }
      __syncthreads();
      for (int p = half; p < np; p += 2) {
        float y = pa[p][0] * wc0 + pa[p][1] * wc1 + pa[p][2] * wc2;
        s += y;
        ss += y * y;
      }
    }
    __syncthreads();
    float* red = (float*)pa;
    red[t] = s;
    red[256 + t] = ss;
    __syncthreads();
    if (t < 128) {
      partials2[blockIdx.x * CIN + t] = red[t] + red[128 + t];
      partials2[NB2 * CIN + blockIdx.x * CIN + t] =
          red[256 + t] + red[256 + 128 + t];
    }
  } else {
    // ---- cscan ----
    int* wsum = (int*)smem;
    int s0 = ccnt[2 * t], s1 = ccnt[2 * t + 1];
    int s = s0 + s1;
    int l = t & 63, w = t >> 6;
    int ss = s;
    for (int off = 1; off < 64; off <<= 1) {
      int v = __shfl_up(ss, off);
      if (l >= off) ss += v;
    }
    if (l == 63) wsum[w] = ss;
    __syncthreads();
    int wb = 0;
#pragma unroll
    for (int i = 0; i < 4; ++i)
      if (i < w) wb += wsum[i];
    int ex = wb + ss - s;
    sbase[2 * t] = ex;
    sbase[2 * t + 1] = ex + s0;
    bcur[2 * t] = ex;
    bcur[2 * t + 1] = ex + s0;
    if (t == 255) sbase[NBKT_MAX] = wb + ss;
  }
}

// ---------------- fuseC: red2 (1) | prep2 (5) | bucket1 (rest) -----------------
__global__ __launch_bounds__(256) void k_fuseC(
    const float* __restrict__ partials1, const float* __restrict__ partials2,
    float* __restrict__ stats1, float* __restrict__ stats2,
    const __hip_bfloat16* __restrict__ w3b,
    const __hip_bfloat16* __restrict__ wqT,
    const __hip_bfloat16* __restrict__ wvT, const float* __restrict__ wq,
    const float* __restrict__ wv, const float* __restrict__ b3,
    const float* __restrict__ bq, const float* __restrict__ bv,
    __hip_bfloat16* __restrict__ W3qT, __hip_bfloat16* __restrict__ W3vT,
    float* __restrict__ bqp, float* __restrict__ bvp,
    const int* __restrict__ q_idx, const int* __restrict__ k_idx,
    const int* __restrict__ kernel_idx, int* __restrict__ bcur,
    unsigned* __restrict__ stg, int M) {
  __shared__ __align__(16) char smem[22544];
  int bid = blockIdx.x;
  int t = threadIdx.x;
  if (bid == 0) {
    // ---- red2 ----
    if (t < 128) {
      float s = 0.f, ss = 0.f;
      for (int b = 0; b < NB2; ++b) {
        s += partials2[b * CIN + t];
        ss += partials2[NB2 * CIN + b * CIN + t];
      }
      stats2[t] = s;
      stats2[CIN + t] = ss;
    } else if (t < 134) {
      int j = t - 128;
      float s = 0.f;
      for (int b = 0; b < NB1; ++b) s += partials1[b * 8 + j];
      stats1[j] = s;
    }
  } else if (bid < 6) {
    // ---- prep2 ----
    int pb = bid - 1;
    if (pb == 4) {
      int c = t & 127;
      const float* wsel = (t < 128) ? wq : wv;
      float s = (t < 128) ? bq[c] : bv[c];
      for (int j = 0; j < CIN; ++j) s += b3[j] * wsel[j * CIN + c];
      if (t < 128)
        bqp[c] = s;
      else
        bvp[c] = s;
      return;
    }
    int n0 = pb * 32;
    int w = t >> 6, l = t & 63;
    int lr = l & 15, lg = l >> 4;
    int colbase = w * 32;
    f32x4 cq[2][2], cv[2][2];
#pragma unroll
    for (int mt = 0; mt < 2; ++mt)
#pragma unroll
      for (int nt = 0; nt < 2; ++nt) {
        cq[mt][nt] = {0.f, 0.f, 0.f, 0.f};
        cv[mt][nt] = {0.f, 0.f, 0.f, 0.f};
      }
#pragma unroll
    for (int kk = 0; kk < 4; ++kk) {
      short8 aA[2], bQ[2], bV[2];
#pragma unroll
      for (int mt = 0; mt < 2; ++mt)
        aA[mt] = *(const short8*)(w3b + (size_t)(n0 + mt * 16 + lr) * CIN +
                                  kk * 32 + lg * 8);
#pragma unroll
      for (int nt = 0; nt < 2; ++nt) {
        size_t off = (size_t)(colbase + nt * 16 + lr) * CIN + kk * 32 + lg * 8;
        bQ[nt] = *(const short8*)(wqT + off);
        bV[nt] = *(const short8*)(wvT + off);
      }
#pragma unroll
      for (int mt = 0; mt < 2; ++mt)
#pragma unroll
        for (int nt = 0; nt < 2; ++nt) {
          cq[mt][nt] = __builtin_amdgcn_mfma_f32_16x16x32_bf16(
              aA[mt], bQ[nt], cq[mt][nt], 0, 0, 0);
          cv[mt][nt] = __builtin_amdgcn_mfma_f32_16x16x32_bf16(
              aA[mt], bV[nt], cv[mt][nt], 0, 0, 0);
        }
    }
#pragma unroll
    for (int mt = 0; mt < 2; ++mt)
#pragma unroll
      for (int nt = 0; nt < 2; ++nt)
#pragma unroll
        for (int r = 0; r < 4; ++r) {
          int k = n0 + mt * 16 + lg * 4 + r;
          int c = colbase + nt * 16 + lr;
          W3qT[(size_t)c * CIN + k] = __float2bfloat16(cq[mt][nt][r]);
          W3vT[(size_t)c * CIN + k] = __float2bfloat16(cv[mt][nt][r]);
        }
  } else {
    // ---- bucket1 ----
    int* lhist = (int*)smem;
    int* loffs = (int*)(smem + 2048);
    int* lcur = (int*)(smem + 4096);
    int* wsum = (int*)(smem + 6144);
    unsigned* buf = (unsigned*)(smem + 6160);
    int base = (bid - 6) * CH;
    for (int b = t; b < NBKT_MAX; b += 256) lhist[b] = 0;
    __syncthreads();

    int qv_[16];
#pragma unroll
    for (int j = 0; j < 16; ++j) {
      int i = base + t + j * 256;
      int q = (i < M) ? q_idx[i] : -1;
      qv_[j] = q;
      if (q >= 0) atomicAdd(&lhist[q >> 8], 1);
    }
    __syncthreads();

    {
      int s0 = lhist[2 * t], s1 = lhist[2 * t + 1];
      int s = s0 + s1;
      int l = t & 63, w = t >> 6;
      int ss = s;
      for (int off = 1; off < 64; off <<= 1) {
        int v = __shfl_up(ss, off);
        if (l >= off) ss += v;
      }
      if (l == 63) wsum[w] = ss;
      __syncthreads();
      int wb = 0;
#pragma unroll
      for (int i = 0; i < 4; ++i)
        if (i < w) wb += wsum[i];
      int ex = wb + ss - s;
      loffs[2 * t] = ex;
      loffs[2 * t + 1] = ex + s0;
      lcur[2 * t] = ex;
      lcur[2 * t + 1] = ex + s0;
    }
    __syncthreads();

#pragma unroll
    for (int j = 0; j < 16; ++j) {
      int q = qv_[j];
      if (q >= 0) {
        int i = base + t + j * 256;
        unsigned e = (unsigned)k_idx[i] | ((unsigned)kernel_idx[i] << 17) |
                     ((unsigned)(q & 255) << 22);
        int d = atomicAdd(&lcur[q >> 8], 1);
        buf[d] = e;
      }
    }
    __syncthreads();

    for (int b = t; b < NBKT_MAX; b += 256) {
      int cntb = lhist[b];
      if (cntb > 0) {
        int g = atomicAdd(&bcur[b], cntb);
        int lo = loffs[b];
        for (int j = 0; j < cntb; ++j) stg[g + j] = buf[lo + j];
      }
    }
  }
}

// ---------------- bucket2a: per-q counts from staging --------------------------
__global__ __launch_bounds__(256) void k_bucket2a(
    const unsigned* __restrict__ stg, const int* __restrict__ sbase,
    int* __restrict__ cnt, int N) {
  __shared__ int lh[256];
  int b = blockIdx.x;
  int t = threadIdx.x;
  lh[t] = 0;
  __syncthreads();
  int start = sbase[b];
  int bcnt = sbase[b + 1] - start;
  for (int i = t; i < bcnt; i += 256) atomicAdd(&lh[stg[start + i] >> 22], 1);
  __syncthreads();
  int q = (b << 8) + t;
  if (q < N) cnt[q] = lh[t];
}

// ---------------- scans --------------------------------------------------------
__global__ __launch_bounds__(256) void k_scan1(const int* __restrict__ cnt,
                                               int* __restrict__ poffs,
                                               int* __restrict__ bsum, int N) {
  __shared__ int ws_[4];
  int t = threadIdx.x;
  int l = t & 63, w = t >> 6;
  int base = blockIdx.x * 1024 + t * 4;
  int pc[4];
  int s = 0;
#pragma unroll
  for (int j = 0; j < 4; ++j) {
    int c = (base + j < N) ? cnt[base + j] : 0;
    pc[j] = (c + 7) & ~7;
    s += pc[j];
  }
  int own = s;
  for (int off = 1; off < 64; off <<= 1) {
    int v = __shfl_up(s, off);
    if (l >= off) s += v;
  }
  if (l == 63) ws_[w] = s;
  __syncthreads();
  int wbase = 0;
#pragma unroll
  for (int i = 0; i < 4; ++i)
    if (i < w) wbase += ws_[i];
  int ex = wbase + s - own;
#pragma unroll
  for (int j = 0; j < 4; ++j) {
    if (base + j < N) poffs[base + j] = ex;
    ex += pc[j];
  }
  if (t == 255) bsum[blockIdx.x] = wbase + s;
}

__global__ __launch_bounds__(256) void k_scan2(int* __restrict__ bsum,
                                               int* __restrict__ bbase, int NB,
                                               int* __restrict__ poffsN) {
  __shared__ int ws_[4];
  int t = threadIdx.x;
  int l = t & 63, w = t >> 6;
  int s = (t < NB) ? bsum[t] : 0;
  int own = s;
  for (int off = 1; off < 64; off <<= 1) {
    int v = __shfl_up(s, off);
    if (l >= off) s += v;
  }
  if (l == 63) ws_[w] = s;
  __syncthreads();
  int wbase = 0;
#pragma unroll
  for (int i = 0; i < 4; ++i)
    if (i < w) wbase += ws_[i];
  if (t < NB) bbase[t] = wbase + s - own;
  if (t == 255) *poffsN = wbase + s;
}

__global__ __launch_bounds__(256) void k_scan3(const int* __restrict__ cnt,
                                               int* __restrict__ poffs,
                                               const int* __restrict__ bbase,
                                               unsigned* __restrict__ recs,
                                               int N) {
  int t = threadIdx.x;
  int base = blockIdx.x * 1024 + t * 4;
  int bb = bbase[blockIdx.x];
#pragma unroll
  for (int j = 0; j < 4; ++j) {
    int i = base + j;
    if (i >= N) break;
    int o = poffs[i] + bb;
    poffs[i] = o;
    int c = cnt[i];
    int pcend = o + ((c + 7) & ~7);
    for (int p = o + c; p < pcend; ++p) recs[p] = 27u << 17;
  }
}

// ---------------- fused: bucket2b (NBKT blocks) | qv (rest) --------------------
__global__ __launch_bounds__(256) void k_qv_b2b(
    const unsigned* __restrict__ stg, const int* __restrict__ sbase,
    const int* __restrict__ poffs, unsigned* __restrict__ recs, int NBKT,
    const float* __restrict__ points, const float* __restrict__ feats,
    const float* __restrict__ w1, const float* __restrict__ g1,
    const float* __restrict__ b1, const float* __restrict__ w2,
    const float* __restrict__ g2, const float* __restrict__ b2,
    const __hip_bfloat16* __restrict__ wqT,
    const __hip_bfloat16* __restrict__ wvT,
    const __hip_bfloat16* __restrict__ W3qT,
    const __hip_bfloat16* __restrict__ W3vT, const float* __restrict__ bqp,
    const float* __restrict__ bvp, const float* __restrict__ stats1,
    const float* __restrict__ stats2, __hip_bfloat16* __restrict__ qnout,
    __hip_bfloat16* __restrict__ vout, int N) {
  __shared__ __align__(16) char smem[17792];
  int t = threadIdx.x;
  if ((int)blockIdx.x < NBKT) {
    // ---- bucket2b ----
    int* qcur = (int*)smem;
    int b = blockIdx.x;
    int qbase = b << 8;
    int q = qbase + t;
    qcur[t] = (q < N) ? poffs[q] : 0;
    __syncthreads();
    int start = sbase[b];
    int bcnt = sbase[b + 1] - start;
    for (int i = t; i < bcnt; i += 256) {
      unsigned e = stg[start + i];
      int ql = e >> 22;
      unsigned rec = e & 0x3FFFFFu;
      int pos = atomicAdd(&qcur[ql], 1);
      recs[pos] = rec;
    }
    return;
  }
  // ---- qv ----
  float(*h0s)[3] = (float(*)[3])smem;                                // 384 B
  __hip_bfloat16(*h1s)[136] = (__hip_bfloat16(*)[136])(smem + 384);  // 8704 B
  __hip_bfloat16(*fs)[136] = (__hip_bfloat16(*)[136])(smem + 9088);  // 8704 B

  int n0 = ((int)blockIdx.x - NBKT) * 32;

  int frow = t >> 3, fpart = t & 7;
  int fn = n0 + frow;
  float4 f0 = {0.f, 0.f, 0.f, 0.f}, f1 = f0, f2 = f0, f3 = f0;
  if (fn < N) {
    const float4* src = (const float4*)(feats + (size_t)fn * CIN + fpart * 16);
    f0 = src[0];
    f1 = src[1];
    f2 = src[2];
    f3 = src[3];
  }

  if (t < 32) {
    int n = n0 + t;
    float p0 = 0.f, p1 = 0.f, p2 = 0.f;
    if (n < N) {
      p0 = points[3 * n];
      p1 = points[3 * n + 1];
      p2 = points[3 * n + 2];
    }
#pragma unroll
    for (int j = 0; j < 3; ++j) {
      float m = stats1[j] / (float)N;
      float var = stats1[3 + j] / (float)N - m * m;
      float sc = rsqrtf(var + EPS_BN) * g1[j];
      float sh = b1[j] - m * sc;
      float y = p0 * w1[j] + p1 * w1[3 + j] + p2 * w1[6 + j];
      h0s[t][j] = fmaxf(y * sc + sh, 0.f);
    }
  }

  {
    unsigned u[8];
    u[0] = pk2bf(f0.x, f0.y);
    u[1] = pk2bf(f0.z, f0.w);
    u[2] = pk2bf(f1.x, f1.y);
    u[3] = pk2bf(f1.z, f1.w);
    u[4] = pk2bf(f2.x, f2.y);
    u[5] = pk2bf(f2.z, f2.w);
    u[6] = pk2bf(f3.x, f3.y);
    u[7] = pk2bf(f3.z, f3.w);
    unsigned* dst = (unsigned*)((char*)&fs[frow][0] + fpart * 32);
#pragma unroll
    for (int i = 0; i < 8; ++i) dst[i] = u[i];
  }
  __syncthreads();

  {
    int c = t & 127, half = t >> 7;
    float m2 = stats2[c] / (float)N;
    float v2 = stats2[CIN + c] / (float)N - m2 * m2;
    float sc2 = rsqrtf(v2 + EPS_BN) * g2[c];
    float sh2 = b2[c] - m2 * sc2;
    float wc0 = w2[c], wc1 = w2[CIN + c], wc2 = w2[2 * CIN + c];
#pragma unroll
    for (int i = 0; i < 16; ++i) {
      int p = i * 2 + half;
      float y = h0s[p][0] * wc0 + h0s[p][1] * wc1 + h0s[p][2] * wc2;
      h1s[p][c] = __float2bfloat16(fmaxf(y * sc2 + sh2, 0.f));
    }
  }
  __syncthreads();

  int w = t >> 6, l = t & 63;
  int lr = l & 15, lg = l >> 4;
  int colbase = w * 32;

  f32x4 aq[2][2], av[2][2];
#pragma unroll
  for (int nt = 0; nt < 2; ++nt) {
    float bqc = bqp[colbase + nt * 16 + lr];
    float bvc = bvp[colbase + nt * 16 + lr];
#pragma unroll
    for (int mt = 0; mt < 2; ++mt) {
      aq[mt][nt] = {bqc, bqc, bqc, bqc};
      av[mt][nt] = {bvc, bvc, bvc, bvc};
    }
  }
#pragma unroll
  for (int kk = 0; kk < 4; ++kk) {
    short8 aF[2], aH[2];
#pragma unroll
    for (int mt = 0; mt < 2; ++mt) {
      aF[mt] = *(const short8*)((const char*)fs + (mt * 16 + lr) * 272 +
                                (kk * 32 + lg * 8) * 2);
      aH[mt] = *(const short8*)((const char*)h1s + (mt * 16 + lr) * 272 +
                                (kk * 32 + lg * 8) * 2);
    }
    short8 bQf[2], bQh[2], bVf[2], bVh[2];
#pragma unroll
    for (int nt = 0; nt < 2; ++nt) {
      size_t off =
          ((size_t)(colbase + nt * 16 + lr) * CIN + kk * 32 + lg * 8) * 2;
      bQf[nt] = *(const short8*)((const char*)wqT + off);
      bQh[nt] = *(const short8*)((const char*)W3qT + off);
      bVf[nt] = *(const short8*)((const char*)wvT + off);
      bVh[nt] = *(const short8*)((const char*)W3vT + off);
    }
#pragma unroll
    for (int mt = 0; mt < 2; ++mt)
#pragma unroll
      for (int nt = 0; nt < 2; ++nt) {
        aq[mt][nt] = __builtin_amdgcn_mfma_f32_16x16x32_bf16(aF[mt], bQf[nt],
                                                             aq[mt][nt], 0, 0, 0);
        aq[mt][nt] = __builtin_amdgcn_mfma_f32_16x16x32_bf16(aH[mt], bQh[nt],
                                                             aq[mt][nt], 0, 0, 0);
        av[mt][nt] = __builtin_amdgcn_mfma_f32_16x16x32_bf16(aF[mt], bVf[nt],
                                                             av[mt][nt], 0, 0, 0);
        av[mt][nt] = __builtin_amdgcn_mfma_f32_16x16x32_bf16(aH[mt], bVh[nt],
                                                             av[mt][nt], 0, 0, 0);
      }
  }
  __syncthreads();

#pragma unroll
  for (int mt = 0; mt < 2; ++mt)
#pragma unroll
    for (int nt = 0; nt < 2; ++nt)
#pragma unroll
      for (int r = 0; r < 4; ++r) {
        float q = aq[mt][nt][r];
        float s = q * q;
        s += __shfl_xor(s, 1);
        s += __shfl_xor(s, 2);
        s += __shfl_xor(s, 4);
        s += __shfl_xor(s, 8);
        float inv = rsqrtf(fmaxf(s, EPS_NORM * EPS_NORM));
        int row = mt * 16 + lg * 4 + r;
        int col = colbase + nt * 16 + lr;
        fs[row][col] = __float2bfloat16(q * inv);
        h1s[row][col] = __float2bfloat16(av[mt][nt][r]);
      }
  __syncthreads();

  {
    int row = t >> 3, part = t & 7;
    int n = n0 + row;
    if (n < N) {
      const char* srcq = (const char*)&fs[row][0] + part * 32;
      char* dstq = (char*)qnout + (size_t)n * 256 + part * 32;
      *(uint4*)dstq = *(const uint4*)srcq;
      *(uint4*)(dstq + 16) = *(const uint4*)(srcq + 16);
      const char* srcv = (const char*)&h1s[row][0] + part * 32;
      char* dstv = (char*)vout + (size_t)n * 256 + part * 32;
      *(uint4*)dstv = *(const uint4*)srcv;
      *(uint4*)(dstv + 16) = *(const uint4*)(srcv + 16);
    }
  }
}

// ---------------- gather + in-block dots (f32, h-major) + out projection -------
__global__ __launch_bounds__(512) void k_gather_out(
    const unsigned* __restrict__ recs, const int* __restrict__ poffs,
    const __hip_bfloat16* __restrict__ qn, const __hip_bfloat16* __restrict__ v,
    const __hip_bfloat16* __restrict__ pnb,
    const __hip_bfloat16* __restrict__ woT, const float* __restrict__ bo,
    float* __restrict__ out, int N) {
  __shared__ __hip_bfloat16 accs[32][136];
  __shared__ float dotlds[32][224];  // [n-local][h*28 + kk]
  int t = threadIdx.x;
  int w = t >> 6, l = t & 63;
  int h = l >> 3;
  int n0 = blockIdx.x * 32;
  const char* vbase = (const char*)v + 4 * l;

  {
    int row = t >> 4, part = t & 15;
    int n = n0 + row;
    uint4 val = {0u, 0u, 0u, 0u};
    if (n < N)
      val = *(const uint4*)((const char*)qn + (size_t)n * 256 + part * 16);
    *(uint4*)((char*)&accs[row][0] + part * 16) = val;
  }
  __syncthreads();

  {
    int lr = l & 15, lg = l >> 4;
    int rg = w & 1;
    const short8 zero8 = {0, 0, 0, 0, 0, 0, 0, 0};
#pragma unroll
    for (int hh = 0; hh < 2; ++hh) {
      int hx = (w >> 1) * 2 + hh;
      short8 aA = zero8, bB0 = zero8, bB1 = zero8;
      if (lg < 2) {
        aA = *(const short8*)((const char*)&accs[rg * 16 + lr][0] +
                              (hx * CHD + lg * 8) * 2);
        bB0 = *(const short8*)(pnb + lr * CIN + hx * CHD + lg * 8);
        bB1 = *(const short8*)(pnb + (16 + lr) * CIN + hx * CHD + lg * 8);
      }
      f32x4 c0 = {0.f, 0.f, 0.f, 0.f}, c1 = {0.f, 0.f, 0.f, 0.f};
      c0 = __builtin_amdgcn_mfma_f32_16x16x32_bf16(aA, bB0, c0, 0, 0, 0);
      c1 = __builtin_amdgcn_mfma_f32_16x16x32_bf16(aA, bB1, c1, 0, 0, 0);
#pragma unroll
      for (int r = 0; r < 4; ++r) {
        int row = rg * 16 + lg * 4 + r;
        dotlds[row][hx * 28 + lr] = c0[r];
        if (lr < 12) dotlds[row][hx * 28 + 16 + lr] = c1[r];
      }
    }
  }
  __syncthreads();

  int hb = h * 28;
#pragma unroll 1
  for (int j = 0; j < 4; ++j) {
    int nl = w * 4 + j;
    int n = n0 + nl;
    float ax = 0.f, ay = 0.f;
    if (n < N) {
      const float* dptr = &dotlds[nl][0];
      int beg = poffs[n], end = poffs[n + 1];
      for (int idx = beg; idx < end; idx += 8) {
        unsigned r0 = __builtin_nontemporal_load(&recs[idx + 0]);
        unsigned r1 = __builtin_nontemporal_load(&recs[idx + 1]);
        unsigned r2 = __builtin_nontemporal_load(&recs[idx + 2]);
        unsigned r3 = __builtin_nontemporal_load(&recs[idx + 3]);
        unsigned r4 = __builtin_nontemporal_load(&recs[idx + 4]);
        unsigned r5 = __builtin_nontemporal_load(&recs[idx + 5]);
        unsigned r6 = __builtin_nontemporal_load(&recs[idx + 6]);
        unsigned r7 = __builtin_nontemporal_load(&recs[idx + 7]);
        unsigned v0 = *(const unsigned*)(vbase + (size_t)(r0 & 0x1FFFF) * 256);
        unsigned v1 = *(const unsigned*)(vbase + (size_t)(r1 & 0x1FFFF) * 256);
        unsigned v2 = *(const unsigned*)(vbase + (size_t)(r2 & 0x1FFFF) * 256);
        unsigned v3 = *(const unsigned*)(vbase + (size_t)(r3 & 0x1FFFF) * 256);
        unsigned v4 = *(const unsigned*)(vbase + (size_t)(r4 & 0x1FFFF) * 256);
        unsigned v5 = *(const unsigned*)(vbase + (size_t)(r5 & 0x1FFFF) * 256);
        unsigned v6 = *(const unsigned*)(vbase + (size_t)(r6 & 0x1FFFF) * 256);
        unsigned v7 = *(const unsigned*)(vbase + (size_t)(r7 & 0x1FFFF) * 256);
        float a0 = dptr[hb + (r0 >> 17)];
        float a1 = dptr[hb + (r1 >> 17)];
        float a2 = dptr[hb + (r2 >> 17)];
        float a3 = dptr[hb + (r3 >> 17)];
        float a4 = dptr[hb + (r4 >> 17)];
        float a5 = dptr[hb + (r5 >> 17)];
        float a6 = dptr[hb + (r6 >> 17)];
        float a7 = dptr[hb + (r7 >> 17)];
        ax += a0 * bflo(v0);
        ay += a0 * bfhi(v0);
        ax += a1 * bflo(v1);
        ay += a1 * bfhi(v1);
        ax += a2 * bflo(v2);
        ay += a2 * bfhi(v2);
        ax += a3 * bflo(v3);
        ay += a3 * bfhi(v3);
        ax += a4 * bflo(v4);
        ay += a4 * bfhi(v4);
        ax += a5 * bflo(v5);
        ay += a5 * bfhi(v5);
        ax += a6 * bflo(v6);
        ay += a6 * bfhi(v6);
        ax += a7 * bflo(v7);
        ay += a7 * bfhi(v7);
      }
    }
    __hip_bfloat16 bx = __float2bfloat16(ax), by = __float2bfloat16(ay);
    unsigned pk = (unsigned)*(unsigned short*)&bx |
                  ((unsigned)*(unsigned short*)&by << 16);
    ((unsigned*)((char*)accs + nl * 272))[l] = pk;
  }
  __syncthreads();

  int lr = l & 15, lg = l >> 4;
  int colb = w * 16;
  float bc = bo[colb + lr];
  f32x4 acc0 = {bc, bc, bc, bc}, acc1 = {bc, bc, bc, bc};
#pragma unroll
  for (int kk = 0; kk < 4; ++kk) {
    short8 aA0 = *(const short8*)((const char*)accs + lr * 272 +
                                  (kk * 32 + lg * 8) * 2);
    short8 aA1 = *(const short8*)((const char*)accs + (16 + lr) * 272 +
                                  (kk * 32 + lg * 8) * 2);
    short8 bB = *(const short8*)(woT + (size_t)(colb + lr) * CIN + kk * 32 +
                                 lg * 8);
    acc0 = __builtin_amdgcn_mfma_f32_16x16x32_bf16(aA0, bB, acc0, 0, 0, 0);
    acc1 = __builtin_amdgcn_mfma_f32_16x16x32_bf16(aA1, bB, acc1, 0, 0, 0);
  }
#pragma unroll
  for (int r = 0; r < 4; ++r) {
    int nr0 = n0 + lg * 4 + r;
    int nr1 = nr0 + 16;
    if (nr0 < N)
      __builtin_nontemporal_store(acc0[r], &out[(size_t)nr0 * CIN + colb + lr]);
    if (nr1 < N)
      __builtin_nontemporal_store(acc1[r], &out[(size_t)nr1 * CIN + colb + lr]);
  }
}

// ---------------- launch -------------------------------------------------------
extern "C" void kernel_launch(void* const* d_in, const int* in_sizes, int n_in,
                              void* d_out, int out_size, void* d_ws,
                              size_t ws_size, hipStream_t stream) {
  const float* points = (const float*)d_in[0];
  const float* feats = (const float*)d_in[1];
  const int* k_idx = (const int*)d_in[2];
  const int* q_idx = (const int*)d_in[3];
  const int* kernel_idx = (const int*)d_in[4];
  const float* w1 = (const float*)d_in[5];
  const float* g1 = (const float*)d_in[6];
  const float* b1 = (const float*)d_in[7];
  const float* w2 = (const float*)d_in[8];
  const float* g2 = (const float*)d_in[9];
  const float* b2 = (const float*)d_in[10];
  const float* w3 = (const float*)d_in[11];
  const float* b3 = (const float*)d_in[12];
  const float* wq = (const float*)d_in[13];
  const float* bq = (const float*)d_in[14];
  const float* wv = (const float*)d_in[15];
  const float* bv = (const float*)d_in[16];
  const float* wo = (const float*)d_in[17];
  const float* bo = (const float*)d_in[18];
  const float* pos_enc = (const float*)d_in[19];

  int N = in_sizes[0] / 3;
  int M = in_sizes[2];
  int NB = (N + 1023) / 1024;  // <= 256
  int NBKT = (N + 255) >> 8;   // <= 512
  int Np = (N + 4) & ~3;
  int NB1C = (M + CH - 1) / CH;

  float* ws = (float*)d_ws;
  float* stats1 = ws;                                 // 8
  float* stats2 = ws + 8;                             // 256 (ends 264)
  __hip_bfloat16* pnb = (__hip_bfloat16*)(ws + 264);  // 32*128 bf16 (ends 2312)
  float* bqp = ws + 2312;                             // 128
  float* bvp = ws + 2440;                             // 128 (ends 2568)
  int* cnt = (int*)(ws + 4096);                       // Np
  int* poffs = cnt + Np;                              // Np (N+1 used)
  int* bsum = poffs + Np;                             // 512
  int* bbase = bsum + 512;                            // 512
  int* bcur = bbase + 512;                            // 512
  int* ccnt = bcur + 512;                             // 512
  int* sbase = ccnt + 512;                            // 520 (513 used)
  unsigned* recs = (unsigned*)(sbase + 520);          // recn (padded)
  size_t recn = ((size_t)M + 8 * (size_t)N + 7) & ~(size_t)7;
  unsigned* stg = recs + recn;                          // M
  __hip_bfloat16* qnb = (__hip_bfloat16*)(stg + M);     // N*128
  __hip_bfloat16* vb = qnb + (size_t)N * CIN;           // N*128
  __hip_bfloat16* wqT = vb + (size_t)N * CIN;
  __hip_bfloat16* wvT = wqT + CIN * CIN;
  __hip_bfloat16* woT = wvT + CIN * CIN;
  __hip_bfloat16* W3qT = woT + CIN * CIN;
  __hip_bfloat16* W3vT = W3qT + CIN * CIN;
  __hip_bfloat16* w3b = W3vT + CIN * CIN;
  float* partials1 = (float*)(w3b + CIN * CIN);  // NB1*8
  float* partials2 = partials1 + NB1 * 8;        // 2*NB2*128
  float* outf = (float*)d_out;

  hipMemsetAsync(ccnt, 0, NBKT_MAX * sizeof(int), stream);

  k_fuseA<<<384, 256, 0, stream>>>(points, w1, partials1, pos_enc, wq, wv, wo,
                                   w3, pnb, wqT, wvT, woT, w3b, q_idx, ccnt, N,
                                   M);
  k_fuseB<<<NB2 + 1, 256, 0, stream>>>(points, w1, g1, b1, w2, partials1,
                                       partials2, ccnt, sbase, bcur, N);
  k_fuseC<<<6 + NB1C, 256, 0, stream>>>(partials1, partials2, stats1, stats2,
                                        w3b, wqT, wvT, wq, wv, b3, bq, bv, W3qT,
                                        W3vT, bqp, bvp, q_idx, k_idx,
                                        kernel_idx, bcur, stg, M);
  k_bucket2a<<<NBKT, 256, 0, stream>>>(stg, sbase, cnt, N);
  k_scan1<<<NB, 256, 0, stream>>>(cnt, poffs, bsum, N);
  k_scan2<<<1, 256, 0, stream>>>(bsum, bbase, NB, poffs + N);
  k_scan3<<<NB, 256, 0, stream>>>(cnt, poffs, bbase, recs, N);
  k_qv_b2b<<<NBKT + (N + 31) / 32, 256, 0, stream>>>(
      stg, sbase, poffs, recs, NBKT, points, feats, w1, g1, b1, w2, g2, b2, wqT,
      wvT, W3qT, W3vT, bqp, bvp, stats1, stats2, qnb, vb, N);
  k_gather_out<<<(N + 31) / 32, 512, 0, stream>>>(recs, poffs, qnb, vb, pnb,
                                                  woT, bo, outf, N);
}

// Round 22
// 218.595 us; speedup vs baseline: 1.0236x; 1.0219x over previous
//
#include <hip/hip_runtime.h>
#include <hip/hip_bf16.h>

#define CIN 128
#define NHEAD 8
#define CHD 16
#define KVOL 27
#define NBKT_MAX 512
#define CH 4096
#define NB1 64   // bn1 partial blocks
#define NB2 256  // bn2 partial blocks

constexpr float EPS_BN = 1e-5f;
constexpr float EPS_NORM = 1e-12f;

typedef __attribute__((ext_vector_type(8))) short short8;
typedef __attribute__((ext_vector_type(4))) float f32x4;

__device__ __forceinline__ float bflo(unsigned u) {
  return __uint_as_float(u << 16);
}
__device__ __forceinline__ float bfhi(unsigned u) {
  return __uint_as_float(u & 0xffff0000u);
}
__device__ __forceinline__ unsigned pk2bf(float lo, float hi) {
  __hip_bfloat16 a = __float2bfloat16(lo), b = __float2bfloat16(hi);
  return (unsigned)*(unsigned short*)&a | ((unsigned)*(unsigned short*)&b << 16);
}

// ---------------- fuseA: bn1 partials (64) | prep (64) | chist (256) -----------
__global__ __launch_bounds__(256) void k_fuseA(
    const float* __restrict__ points, const float* __restrict__ w1,
    float* __restrict__ partials1, const float* __restrict__ pos_enc,
    const float* __restrict__ wq, const float* __restrict__ wv,
    const float* __restrict__ wo, const float* __restrict__ w3,
    __hip_bfloat16* __restrict__ pnb, __hip_bfloat16* __restrict__ wqT,
    __hip_bfloat16* __restrict__ wvT, __hip_bfloat16* __restrict__ woT,
    __hip_bfloat16* __restrict__ w3b, const int* __restrict__ q_idx,
    int* __restrict__ ccnt, int N, int M) {
  __shared__ __align__(16) char smem[2048];
  int bid = blockIdx.x;
  int t = threadIdx.x;
  if (bid < 64) {
    // ---- bn1 ----
    float(*red)[6] = (float(*)[6])smem;
    float w[9];
#pragma unroll
    for (int i = 0; i < 9; ++i) w[i] = w1[i];
    float s[3] = {0.f, 0.f, 0.f}, ss[3] = {0.f, 0.f, 0.f};
    for (int n = bid * 256 + t; n < N; n += 64 * 256) {
      float p0 = points[3 * n], p1 = points[3 * n + 1], p2 = points[3 * n + 2];
#pragma unroll
      for (int j = 0; j < 3; ++j) {
        float y = p0 * w[j] + p1 * w[3 + j] + p2 * w[6 + j];
        s[j] += y;
        ss[j] += y * y;
      }
    }
#pragma unroll
    for (int j = 0; j < 3; ++j) {
      for (int off = 32; off > 0; off >>= 1) {
        s[j] += __shfl_down(s[j], off);
        ss[j] += __shfl_down(ss[j], off);
      }
    }
    if ((t & 63) == 0) {
      int wv_ = t >> 6;
#pragma unroll
      for (int j = 0; j < 3; ++j) {
        red[wv_][j] = s[j];
        red[wv_][3 + j] = ss[j];
      }
    }
    __syncthreads();
    if (t < 6) {
      float acc = red[0][t] + red[1][t] + red[2][t] + red[3][t];
      partials1[bid * 8 + t] = acc;
    }
  } else if (bid < 128) {
    // ---- prep ----
    int g = (bid - 64) * 256 + t;
    if (g < 256) {
      int kk = g >> 3, h = g & 7;
      if (kk < KVOL) {
        const float* src = pos_enc + (kk * NHEAD + h) * CHD;
        float vals[CHD];
        float s = 0.f;
#pragma unroll
        for (int i = 0; i < CHD; ++i) {
          vals[i] = src[i];
          s += vals[i] * vals[i];
        }
        float inv = 1.f / fmaxf(sqrtf(s), EPS_NORM);
#pragma unroll
        for (int i = 0; i < CHD; ++i)
          pnb[kk * CIN + h * CHD + i] = __float2bfloat16(vals[i] * inv);
      } else {
#pragma unroll
        for (int i = 0; i < CHD; ++i)
          pnb[kk * CIN + h * CHD + i] = __float2bfloat16(0.f);
      }
    }
    if (g < CIN * CIN) {
      int k = g >> 7, c = g & 127;
      int gt = c * CIN + k;
      wqT[gt] = __float2bfloat16(wq[g]);
      wvT[gt] = __float2bfloat16(wv[g]);
      woT[gt] = __float2bfloat16(wo[g]);
      w3b[g] = __float2bfloat16(w3[g]);
    }
  } else {
    // ---- chist ----
    int* lh = (int*)smem;
    for (int b = t; b < NBKT_MAX; b += 256) lh[b] = 0;
    __syncthreads();
    for (int i = (bid - 128) * 256 + t; i < M; i += 256 * 256)
      atomicAdd(&lh[q_idx[i] >> 8], 1);
    __syncthreads();
    for (int b = t; b < NBKT_MAX; b += 256) {
      int c = lh[b];
      if (c > 0) atomicAdd(&ccnt[b], c);
    }
  }
}

// ---------------- fuseB: bn2 partials (256) | cscan (1) ------------------------
__global__ __launch_bounds__(256) void k_fuseB(
    const float* __restrict__ points, const float* __restrict__ w1,
    const float* __restrict__ g1, const float* __restrict__ b1,
    const float* __restrict__ w2, const float* __restrict__ partials1,
    float* __restrict__ partials2, const int* __restrict__ ccnt,
    int* __restrict__ sbase, int* __restrict__ bcur, int N) {
  __shared__ __align__(16) char smem[3072];
  int t = threadIdx.x;
  if (blockIdx.x < NB2) {
    // ---- bn2 ----
    float(*pa)[3] = (float(*)[3])smem;
    float w[9];
#pragma unroll
    for (int i = 0; i < 9; ++i) w[i] = w1[i];
    float st[6] = {0.f, 0.f, 0.f, 0.f, 0.f, 0.f};
    for (int b = 0; b < NB1; ++b)
#pragma unroll
      for (int j = 0; j < 6; ++j) st[j] += partials1[b * 8 + j];
    float sc1[3], sh1[3];
#pragma unroll
    for (int j = 0; j < 3; ++j) {
      float m = st[j] / (float)N;
      float var = st[3 + j] / (float)N - m * m;
      float sc = rsqrtf(var + EPS_BN) * g1[j];
      sc1[j] = sc;
      sh1[j] = b1[j] - m * sc;
    }
    int c = t & 127, half = t >> 7;
    float wc0 = w2[c], wc1 = w2[CIN + c], wc2 = w2[2 * CIN + c];
    float s = 0.f, ss = 0.f;
    for (int base = blockIdx.x * 256; base < N; base += NB2 * 256) {
      int np = min(256, N - base);
      __syncthreads();
      if (t < np) {
        int n = base + t;
        float p0 = points[3 * n], p1 = points[3 * n + 1],
              p2 = points[3 * n + 2];
        float y0 = p0 * w[0] + p1 * w[3] + p2 * w[6];
        float y1 = p0 * w[1] + p1 * w[4] + p2 * w[7];
        float y2 = p0 * w[2] + p1 * w[5] + p2 * w[8];
        pa[t][0] = fmaxf(y0 * sc1[0] + sh1[0], 0.f);
        pa[t][1] = fmaxf(y1 * sc1[1] + sh1[1], 0.f);
        pa[t][2] = fmaxf(y2 * sc1[2] + sh1[2], 0.f);
      }
      __syncthreads();
      for (int p = half; p < np; p += 2) {
        float y = pa[p][0] * wc0 + pa[p][1] * wc1 + pa[p][2] * wc2;
        s += y;
        ss += y * y;
      }
    }
    __syncthreads();
    float* red = (float*)pa;
    red[t] = s;
    red[256 + t] = ss;
    __syncthreads();
    if (t < 128) {
      partials2[blockIdx.x * CIN + t] = red[t] + red[128 + t];
      partials2[NB2 * CIN + blockIdx.x * CIN + t] =
          red[256 + t] + red[256 + 128 + t];
    }
  } else {
    // ---- cscan ----
    int* wsum = (int*)smem;
    int s0 = ccnt[2 * t], s1 = ccnt[2 * t + 1];
    int s = s0 + s1;
    int l = t & 63, w = t >> 6;
    int ss = s;
    for (int off = 1; off < 64; off <<= 1) {
      int v = __shfl_up(ss, off);
      if (l >= off) ss += v;
    }
    if (l == 63) wsum[w] = ss;
    __syncthreads();
    int wb = 0;
#pragma unroll
    for (int i = 0; i < 4; ++i)
      if (i < w) wb += wsum[i];
    int ex = wb + ss - s;
    sbase[2 * t] = ex;
    sbase[2 * t + 1] = ex + s0;
    bcur[2 * t] = ex;
    bcur[2 * t + 1] = ex + s0;
    if (t == 255) sbase[NBKT_MAX] = wb + ss;
  }
}

// ---------------- fuseC: red2 (1) | prep2 (5) | bucket1 (rest) -----------------
__global__ __launch_bounds__(256) void k_fuseC(
    const float* __restrict__ partials1, const float* __restrict__ partials2,
    float* __restrict__ stats1, float* __restrict__ stats2,
    const __hip_bfloat16* __restrict__ w3b,
    const __hip_bfloat16* __restrict__ wqT,
    const __hip_bfloat16* __restrict__ wvT, const float* __restrict__ wq,
    const float* __restrict__ wv, const float* __restrict__ b3,
    const float* __restrict__ bq, const float* __restrict__ bv,
    __hip_bfloat16* __restrict__ W3qT, __hip_bfloat16* __restrict__ W3vT,
    float* __restrict__ bqp, float* __restrict__ bvp,
    const int* __restrict__ q_idx, const int* __restrict__ k_idx,
    const int* __restrict__ kernel_idx, int* __restrict__ bcur,
    unsigned* __restrict__ stg, int M) {
  __shared__ __align__(16) char smem[22544];
  int bid = blockIdx.x;
  int t = threadIdx.x;
  if (bid == 0) {
    // ---- red2 ----
    if (t < 128) {
      float s = 0.f, ss = 0.f;
      for (int b = 0; b < NB2; ++b) {
        s += partials2[b * CIN + t];
        ss += partials2[NB2 * CIN + b * CIN + t];
      }
      stats2[t] = s;
      stats2[CIN + t] = ss;
    } else if (t < 134) {
      int j = t - 128;
      float s = 0.f;
      for (int b = 0; b < NB1; ++b) s += partials1[b * 8 + j];
      stats1[j] = s;
    }
  } else if (bid < 6) {
    // ---- prep2 ----
    int pb = bid - 1;
    if (pb == 4) {
      int c = t & 127;
      const float* wsel = (t < 128) ? wq : wv;
      float s = (t < 128) ? bq[c] : bv[c];
      for (int j = 0; j < CIN; ++j) s += b3[j] * wsel[j * CIN + c];
      if (t < 128)
        bqp[c] = s;
      else
        bvp[c] = s;
      return;
    }
    int n0 = pb * 32;
    int w = t >> 6, l = t & 63;
    int lr = l & 15, lg = l >> 4;
    int colbase = w * 32;
    f32x4 cq[2][2], cv[2][2];
#pragma unroll
    for (int mt = 0; mt < 2; ++mt)
#pragma unroll
      for (int nt = 0; nt < 2; ++nt) {
        cq[mt][nt] = {0.f, 0.f, 0.f, 0.f};
        cv[mt][nt] = {0.f, 0.f, 0.f, 0.f};
      }
#pragma unroll
    for (int kk = 0; kk < 4; ++kk) {
      short8 aA[2], bQ[2], bV[2];
#pragma unroll
      for (int mt = 0; mt < 2; ++mt)
        aA[mt] = *(const short8*)(w3b + (size_t)(n0 + mt * 16 + lr) * CIN +
                                  kk * 32 + lg * 8);
#pragma unroll
      for (int nt = 0; nt < 2; ++nt) {
        size_t off = (size_t)(colbase + nt * 16 + lr) * CIN + kk * 32 + lg * 8;
        bQ[nt] = *(const short8*)(wqT + off);
        bV[nt] = *(const short8*)(wvT + off);
      }
#pragma unroll
      for (int mt = 0; mt < 2; ++mt)
#pragma unroll
        for (int nt = 0; nt < 2; ++nt) {
          cq[mt][nt] = __builtin_amdgcn_mfma_f32_16x16x32_bf16(
              aA[mt], bQ[nt], cq[mt][nt], 0, 0, 0);
          cv[mt][nt] = __builtin_amdgcn_mfma_f32_16x16x32_bf16(
              aA[mt], bV[nt], cv[mt][nt], 0, 0, 0);
        }
    }
#pragma unroll
    for (int mt = 0; mt < 2; ++mt)
#pragma unroll
      for (int nt = 0; nt < 2; ++nt)
#pragma unroll
        for (int r = 0; r < 4; ++r) {
          int k = n0 + mt * 16 + lg * 4 + r;
          int c = colbase + nt * 16 + lr;
          W3qT[(size_t)c * CIN + k] = __float2bfloat16(cq[mt][nt][r]);
          W3vT[(size_t)c * CIN + k] = __float2bfloat16(cv[mt][nt][r]);
        }
  } else {
    // ---- bucket1 ----
    int* lhist = (int*)smem;
    int* loffs = (int*)(smem + 2048);
    int* lcur = (int*)(smem + 4096);
    int* wsum = (int*)(smem + 6144);
    unsigned* buf = (unsigned*)(smem + 6160);
    int base = (bid - 6) * CH;
    for (int b = t; b < NBKT_MAX; b += 256) lhist[b] = 0;
    __syncthreads();

    int qv_[16];
#pragma unroll
    for (int j = 0; j < 16; ++j) {
      int i = base + t + j * 256;
      int q = (i < M) ? q_idx[i] : -1;
      qv_[j] = q;
      if (q >= 0) atomicAdd(&lhist[q >> 8], 1);
    }
    __syncthreads();

    {
      int s0 = lhist[2 * t], s1 = lhist[2 * t + 1];
      int s = s0 + s1;
      int l = t & 63, w = t >> 6;
      int ss = s;
      for (int off = 1; off < 64; off <<= 1) {
        int v = __shfl_up(ss, off);
        if (l >= off) ss += v;
      }
      if (l == 63) wsum[w] = ss;
      __syncthreads();
      int wb = 0;
#pragma unroll
      for (int i = 0; i < 4; ++i)
        if (i < w) wb += wsum[i];
      int ex = wb + ss - s;
      loffs[2 * t] = ex;
      loffs[2 * t + 1] = ex + s0;
      lcur[2 * t] = ex;
      lcur[2 * t + 1] = ex + s0;
    }
    __syncthreads();

#pragma unroll
    for (int j = 0; j < 16; ++j) {
      int q = qv_[j];
      if (q >= 0) {
        int i = base + t + j * 256;
        unsigned e = (unsigned)k_idx[i] | ((unsigned)kernel_idx[i] << 17) |
                     ((unsigned)(q & 255) << 22);
        int d = atomicAdd(&lcur[q >> 8], 1);
        buf[d] = e;
      }
    }
    __syncthreads();

    for (int b = t; b < NBKT_MAX; b += 256) {
      int cntb = lhist[b];
      if (cntb > 0) {
        int g = atomicAdd(&bcur[b], cntb);
        int lo = loffs[b];
        for (int j = 0; j < cntb; ++j) stg[g + j] = buf[lo + j];
      }
    }
  }
}

// ---------------- bucket2a: per-q counts from staging --------------------------
__global__ __launch_bounds__(256) void k_bucket2a(
    const unsigned* __restrict__ stg, const int* __restrict__ sbase,
    int* __restrict__ cnt, int N) {
  __shared__ int lh[256];
  int b = blockIdx.x;
  int t = threadIdx.x;
  lh[t] = 0;
  __syncthreads();
  int start = sbase[b];
  int bcnt = sbase[b + 1] - start;
  for (int i = t; i < bcnt; i += 256) atomicAdd(&lh[stg[start + i] >> 22], 1);
  __syncthreads();
  int q = (b << 8) + t;
  if (q < N) cnt[q] = lh[t];
}

// ---------------- scans --------------------------------------------------------
__global__ __launch_bounds__(256) void k_scan1(const int* __restrict__ cnt,
                                               int* __restrict__ poffs,
                                               int* __restrict__ bsum, int N) {
  __shared__ int ws_[4];
  int t = threadIdx.x;
  int l = t & 63, w = t >> 6;
  int base = blockIdx.x * 1024 + t * 4;
  int pc[4];
  int s = 0;
#pragma unroll
  for (int j = 0; j < 4; ++j) {
    int c = (base + j < N) ? cnt[base + j] : 0;
    pc[j] = (c + 7) & ~7;
    s += pc[j];
  }
  int own = s;
  for (int off = 1; off < 64; off <<= 1) {
    int v = __shfl_up(s, off);
    if (l >= off) s += v;
  }
  if (l == 63) ws_[w] = s;
  __syncthreads();
  int wbase = 0;
#pragma unroll
  for (int i = 0; i < 4; ++i)
    if (i < w) wbase += ws_[i];
  int ex = wbase + s - own;
#pragma unroll
  for (int j = 0; j < 4; ++j) {
    if (base + j < N) poffs[base + j] = ex;
    ex += pc[j];
  }
  if (t == 255) bsum[blockIdx.x] = wbase + s;
}

__global__ __launch_bounds__(256) void k_scan2(int* __restrict__ bsum,
                                               int* __restrict__ bbase, int NB,
                                               int* __restrict__ poffsN) {
  __shared__ int ws_[4];
  int t = threadIdx.x;
  int l = t & 63, w = t >> 6;
  int s = (t < NB) ? bsum[t] : 0;
  int own = s;
  for (int off = 1; off < 64; off <<= 1) {
    int v = __shfl_up(s, off);
    if (l >= off) s += v;
  }
  if (l == 63) ws_[w] = s;
  __syncthreads();
  int wbase = 0;
#pragma unroll
  for (int i = 0; i < 4; ++i)
    if (i < w) wbase += ws_[i];
  if (t < NB) bbase[t] = wbase + s - own;
  if (t == 255) *poffsN = wbase + s;
}

__global__ __launch_bounds__(256) void k_scan3(const int* __restrict__ cnt,
                                               int* __restrict__ poffs,
                                               const int* __restrict__ bbase,
                                               unsigned* __restrict__ recs,
                                               int N) {
  int t = threadIdx.x;
  int base = blockIdx.x * 1024 + t * 4;
  int bb = bbase[blockIdx.x];
#pragma unroll
  for (int j = 0; j < 4; ++j) {
    int i = base + j;
    if (i >= N) break;
    int o = poffs[i] + bb;
    poffs[i] = o;
    int c = cnt[i];
    int pcend = o + ((c + 7) & ~7);
    for (int p = o + c; p < pcend; ++p) recs[p] = 27u << 17;
  }
}

// ---------------- fused: bucket2b (NBKT blocks) | qv (rest) --------------------
__global__ __launch_bounds__(256) void k_qv_b2b(
    const unsigned* __restrict__ stg, const int* __restrict__ sbase,
    const int* __restrict__ poffs, unsigned* __restrict__ recs, int NBKT,
    const float* __restrict__ points, const float* __restrict__ feats,
    const float* __restrict__ w1, const float* __restrict__ g1,
    const float* __restrict__ b1, const float* __restrict__ w2,
    const float* __restrict__ g2, const float* __restrict__ b2,
    const __hip_bfloat16* __restrict__ wqT,
    const __hip_bfloat16* __restrict__ wvT,
    const __hip_bfloat16* __restrict__ W3qT,
    const __hip_bfloat16* __restrict__ W3vT, const float* __restrict__ bqp,
    const float* __restrict__ bvp, const float* __restrict__ stats1,
    const float* __restrict__ stats2, __hip_bfloat16* __restrict__ qnout,
    __hip_bfloat16* __restrict__ vout, int N) {
  __shared__ __align__(16) char smem[17792];
  int t = threadIdx.x;
  if ((int)blockIdx.x < NBKT) {
    // ---- bucket2b ----
    int* qcur = (int*)smem;
    int b = blockIdx.x;
    int qbase = b << 8;
    int q = qbase + t;
    qcur[t] = (q < N) ? poffs[q] : 0;
    __syncthreads();
    int start = sbase[b];
    int bcnt = sbase[b + 1] - start;
    for (int i = t; i < bcnt; i += 256) {
      unsigned e = stg[start + i];
      int ql = e >> 22;
      unsigned rec = e & 0x3FFFFFu;
      int pos = atomicAdd(&qcur[ql], 1);
      recs[pos] = rec;
    }
    return;
  }
  // ---- qv ----
  float(*h0s)[3] = (float(*)[3])smem;                                // 384 B
  __hip_bfloat16(*h1s)[136] = (__hip_bfloat16(*)[136])(smem + 384);  // 8704 B
  __hip_bfloat16(*fs)[136] = (__hip_bfloat16(*)[136])(smem + 9088);  // 8704 B

  int n0 = ((int)blockIdx.x - NBKT) * 32;

  int frow = t >> 3, fpart = t & 7;
  int fn = n0 + frow;
  float4 f0 = {0.f, 0.f, 0.f, 0.f}, f1 = f0, f2 = f0, f3 = f0;
  if (fn < N) {
    const float4* src = (const float4*)(feats + (size_t)fn * CIN + fpart * 16);
    f0 = src[0];
    f1 = src[1];
    f2 = src[2];
    f3 = src[3];
  }

  if (t < 32) {
    int n = n0 + t;
    float p0 = 0.f, p1 = 0.f, p2 = 0.f;
    if (n < N) {
      p0 = points[3 * n];
      p1 = points[3 * n + 1];
      p2 = points[3 * n + 2];
    }
#pragma unroll
    for (int j = 0; j < 3; ++j) {
      float m = stats1[j] / (float)N;
      float var = stats1[3 + j] / (float)N - m * m;
      float sc = rsqrtf(var + EPS_BN) * g1[j];
      float sh = b1[j] - m * sc;
      float y = p0 * w1[j] + p1 * w1[3 + j] + p2 * w1[6 + j];
      h0s[t][j] = fmaxf(y * sc + sh, 0.f);
    }
  }

  {
    unsigned u[8];
    u[0] = pk2bf(f0.x, f0.y);
    u[1] = pk2bf(f0.z, f0.w);
    u[2] = pk2bf(f1.x, f1.y);
    u[3] = pk2bf(f1.z, f1.w);
    u[4] = pk2bf(f2.x, f2.y);
    u[5] = pk2bf(f2.z, f2.w);
    u[6] = pk2bf(f3.x, f3.y);
    u[7] = pk2bf(f3.z, f3.w);
    unsigned* dst = (unsigned*)((char*)&fs[frow][0] + fpart * 32);
#pragma unroll
    for (int i = 0; i < 8; ++i) dst[i] = u[i];
  }
  __syncthreads();

  {
    int c = t & 127, half = t >> 7;
    float m2 = stats2[c] / (float)N;
    float v2 = stats2[CIN + c] / (float)N - m2 * m2;
    float sc2 = rsqrtf(v2 + EPS_BN) * g2[c];
    float sh2 = b2[c] - m2 * sc2;
    float wc0 = w2[c], wc1 = w2[CIN + c], wc2 = w2[2 * CIN + c];
#pragma unroll
    for (int i = 0; i < 16; ++i) {
      int p = i * 2 + half;
      float y = h0s[p][0] * wc0 + h0s[p][1] * wc1 + h0s[p][2] * wc2;
      h1s[p][c] = __float2bfloat16(fmaxf(y * sc2 + sh2, 0.f));
    }
  }
  __syncthreads();

  int w = t >> 6, l = t & 63;
  int lr = l & 15, lg = l >> 4;
  int colbase = w * 32;

  f32x4 aq[2][2], av[2][2];
#pragma unroll
  for (int nt = 0; nt < 2; ++nt) {
    float bqc = bqp[colbase + nt * 16 + lr];
    float bvc = bvp[colbase + nt * 16 + lr];
#pragma unroll
    for (int mt = 0; mt < 2; ++mt) {
      aq[mt][nt] = {bqc, bqc, bqc, bqc};
      av[mt][nt] = {bvc, bvc, bvc, bvc};
    }
  }
#pragma unroll
  for (int kk = 0; kk < 4; ++kk) {
    short8 aF[2], aH[2];
#pragma unroll
    for (int mt = 0; mt < 2; ++mt) {
      aF[mt] = *(const short8*)((const char*)fs + (mt * 16 + lr) * 272 +
                                (kk * 32 + lg * 8) * 2);
      aH[mt] = *(const short8*)((const char*)h1s + (mt * 16 + lr) * 272 +
                                (kk * 32 + lg * 8) * 2);
    }
    short8 bQf[2], bQh[2], bVf[2], bVh[2];
#pragma unroll
    for (int nt = 0; nt < 2; ++nt) {
      size_t off =
          ((size_t)(colbase + nt * 16 + lr) * CIN + kk * 32 + lg * 8) * 2;
      bQf[nt] = *(const short8*)((const char*)wqT + off);
      bQh[nt] = *(const short8*)((const char*)W3qT + off);
      bVf[nt] = *(const short8*)((const char*)wvT + off);
      bVh[nt] = *(const short8*)((const char*)W3vT + off);
    }
#pragma unroll
    for (int mt = 0; mt < 2; ++mt)
#pragma unroll
      for (int nt = 0; nt < 2; ++nt) {
        aq[mt][nt] = __builtin_amdgcn_mfma_f32_16x16x32_bf16(aF[mt], bQf[nt],
                                                             aq[mt][nt], 0, 0, 0);
        aq[mt][nt] = __builtin_amdgcn_mfma_f32_16x16x32_bf16(aH[mt], bQh[nt],
                                                             aq[mt][nt], 0, 0, 0);
        av[mt][nt] = __builtin_amdgcn_mfma_f32_16x16x32_bf16(aF[mt], bVf[nt],
                                                             av[mt][nt], 0, 0, 0);
        av[mt][nt] = __builtin_amdgcn_mfma_f32_16x16x32_bf16(aH[mt], bVh[nt],
                                                             av[mt][nt], 0, 0, 0);
      }
  }
  __syncthreads();

#pragma unroll
  for (int mt = 0; mt < 2; ++mt)
#pragma unroll
    for (int nt = 0; nt < 2; ++nt)
#pragma unroll
      for (int r = 0; r < 4; ++r) {
        float q = aq[mt][nt][r];
        float s = q * q;
        s += __shfl_xor(s, 1);
        s += __shfl_xor(s, 2);
        s += __shfl_xor(s, 4);
        s += __shfl_xor(s, 8);
        float inv = rsqrtf(fmaxf(s, EPS_NORM * EPS_NORM));
        int row = mt * 16 + lg * 4 + r;
        int col = colbase + nt * 16 + lr;
        fs[row][col] = __float2bfloat16(q * inv);
        h1s[row][col] = __float2bfloat16(av[mt][nt][r]);
      }
  __syncthreads();

  {
    int row = t >> 3, part = t & 7;
    int n = n0 + row;
    if (n < N) {
      const char* srcq = (const char*)&fs[row][0] + part * 32;
      char* dstq = (char*)qnout + (size_t)n * 256 + part * 32;
      *(uint4*)dstq = *(const uint4*)srcq;
      *(uint4*)(dstq + 16) = *(const uint4*)(srcq + 16);
      const char* srcv = (const char*)&h1s[row][0] + part * 32;
      char* dstv = (char*)vout + (size_t)n * 256 + part * 32;
      *(uint4*)dstv = *(const uint4*)srcv;
      *(uint4*)(dstv + 16) = *(const uint4*)(srcv + 16);
    }
  }
}

// ---------------- gather + in-block dots (f32, h-major) + out projection -------
__global__ __launch_bounds__(512) void k_gather_out(
    const unsigned* __restrict__ recs, const int* __restrict__ poffs,
    const __hip_bfloat16* __restrict__ qn, const __hip_bfloat16* __restrict__ v,
    const __hip_bfloat16* __restrict__ pnb,
    const __hip_bfloat16* __restrict__ woT, const float* __restrict__ bo,
    float* __restrict__ out, int N) {
  __shared__ __hip_bfloat16 accs[32][136];
  __shared__ float dotlds[32][224];  // [n-local][h*28 + kk]
  int t = threadIdx.x;
  int w = t >> 6, l = t & 63;
  int h = l >> 3;
  int n0 = blockIdx.x * 32;
  const char* vbase = (const char*)v + 4 * l;

  {
    int row = t >> 4, part = t & 15;
    int n = n0 + row;
    uint4 val = {0u, 0u, 0u, 0u};
    if (n < N)
      val = *(const uint4*)((const char*)qn + (size_t)n * 256 + part * 16);
    *(uint4*)((char*)&accs[row][0] + part * 16) = val;
  }
  __syncthreads();

  {
    int lr = l & 15, lg = l >> 4;
    int rg = w & 1;
    const short8 zero8 = {0, 0, 0, 0, 0, 0, 0, 0};
#pragma unroll
    for (int hh = 0; hh < 2; ++hh) {
      int hx = (w >> 1) * 2 + hh;
      short8 aA = zero8, bB0 = zero8, bB1 = zero8;
      if (lg < 2) {
        aA = *(const short8*)((const char*)&accs[rg * 16 + lr][0] +
                              (hx * CHD + lg * 8) * 2);
        bB0 = *(const short8*)(pnb + lr * CIN + hx * CHD + lg * 8);
        bB1 = *(const short8*)(pnb + (16 + lr) * CIN + hx * CHD + lg * 8);
      }
      f32x4 c0 = {0.f, 0.f, 0.f, 0.f}, c1 = {0.f, 0.f, 0.f, 0.f};
      c0 = __builtin_amdgcn_mfma_f32_16x16x32_bf16(aA, bB0, c0, 0, 0, 0);
      c1 = __builtin_amdgcn_mfma_f32_16x16x32_bf16(aA, bB1, c1, 0, 0, 0);
#pragma unroll
      for (int r = 0; r < 4; ++r) {
        int row = rg * 16 + lg * 4 + r;
        dotlds[row][hx * 28 + lr] = c0[r];
        if (lr < 12) dotlds[row][hx * 28 + 16 + lr] = c1[r];
      }
    }
  }
  __syncthreads();

  int hb = h * 28;
#pragma unroll 1
  for (int j = 0; j < 4; ++j) {
    int nl = w * 4 + j;
    int n = n0 + nl;
    float ax = 0.f, ay = 0.f;
    if (n < N) {
      const float* dptr = &dotlds[nl][0];
      int beg = poffs[n], end = poffs[n + 1];
      for (int idx = beg; idx < end; idx += 8) {
        unsigned r0 = recs[idx + 0], r1 = recs[idx + 1], r2 = recs[idx + 2],
                 r3 = recs[idx + 3], r4 = recs[idx + 4], r5 = recs[idx + 5],
                 r6 = recs[idx + 6], r7 = recs[idx + 7];
        unsigned v0 = *(const unsigned*)(vbase + (size_t)(r0 & 0x1FFFF) * 256);
        unsigned v1 = *(const unsigned*)(vbase + (size_t)(r1 & 0x1FFFF) * 256);
        unsigned v2 = *(const unsigned*)(vbase + (size_t)(r2 & 0x1FFFF) * 256);
        unsigned v3 = *(const unsigned*)(vbase + (size_t)(r3 & 0x1FFFF) * 256);
        unsigned v4 = *(const unsigned*)(vbase + (size_t)(r4 & 0x1FFFF) * 256);
        unsigned v5 = *(const unsigned*)(vbase + (size_t)(r5 & 0x1FFFF) * 256);
        unsigned v6 = *(const unsigned*)(vbase + (size_t)(r6 & 0x1FFFF) * 256);
        unsigned v7 = *(const unsigned*)(vbase + (size_t)(r7 & 0x1FFFF) * 256);
        float a0 = dptr[hb + (r0 >> 17)];
        float a1 = dptr[hb + (r1 >> 17)];
        float a2 = dptr[hb + (r2 >> 17)];
        float a3 = dptr[hb + (r3 >> 17)];
        float a4 = dptr[hb + (r4 >> 17)];
        float a5 = dptr[hb + (r5 >> 17)];
        float a6 = dptr[hb + (r6 >> 17)];
        float a7 = dptr[hb + (r7 >> 17)];
        ax += a0 * bflo(v0);
        ay += a0 * bfhi(v0);
        ax += a1 * bflo(v1);
        ay += a1 * bfhi(v1);
        ax += a2 * bflo(v2);
        ay += a2 * bfhi(v2);
        ax += a3 * bflo(v3);
        ay += a3 * bfhi(v3);
        ax += a4 * bflo(v4);
        ay += a4 * bfhi(v4);
        ax += a5 * bflo(v5);
        ay += a5 * bfhi(v5);
        ax += a6 * bflo(v6);
        ay += a6 * bfhi(v6);
        ax += a7 * bflo(v7);
        ay += a7 * bfhi(v7);
      }
    }
    __hip_bfloat16 bx = __float2bfloat16(ax), by = __float2bfloat16(ay);
    unsigned pk = (unsigned)*(unsigned short*)&bx |
                  ((unsigned)*(unsigned short*)&by << 16);
    ((unsigned*)((char*)accs + nl * 272))[l] = pk;
  }
  __syncthreads();

  int lr = l & 15, lg = l >> 4;
  int colb = w * 16;
  float bc = bo[colb + lr];
  f32x4 acc0 = {bc, bc, bc, bc}, acc1 = {bc, bc, bc, bc};
#pragma unroll
  for (int kk = 0; kk < 4; ++kk) {
    short8 aA0 = *(const short8*)((const char*)accs + lr * 272 +
                                  (kk * 32 + lg * 8) * 2);
    short8 aA1 = *(const short8*)((const char*)accs + (16 + lr) * 272 +
                                  (kk * 32 + lg * 8) * 2);
    short8 bB = *(const short8*)(woT + (size_t)(colb + lr) * CIN + kk * 32 +
                                 lg * 8);
    acc0 = __builtin_amdgcn_mfma_f32_16x16x32_bf16(aA0, bB, acc0, 0, 0, 0);
    acc1 = __builtin_amdgcn_mfma_f32_16x16x32_bf16(aA1, bB, acc1, 0, 0, 0);
  }
#pragma unroll
  for (int r = 0; r < 4; ++r) {
    int nr0 = n0 + lg * 4 + r;
    int nr1 = nr0 + 16;
    if (nr0 < N) out[(size_t)nr0 * CIN + colb + lr] = acc0[r];
    if (nr1 < N) out[(size_t)nr1 * CIN + colb + lr] = acc1[r];
  }
}

// ---------------- launch -------------------------------------------------------
extern "C" void kernel_launch(void* const* d_in, const int* in_sizes, int n_in,
                              void* d_out, int out_size, void* d_ws,
                              size_t ws_size, hipStream_t stream) {
  const float* points = (const float*)d_in[0];
  const float* feats = (const float*)d_in[1];
  const int* k_idx = (const int*)d_in[2];
  const int* q_idx = (const int*)d_in[3];
  const int* kernel_idx = (const int*)d_in[4];
  const float* w1 = (const float*)d_in[5];
  const float* g1 = (const float*)d_in[6];
  const float* b1 = (const float*)d_in[7];
  const float* w2 = (const float*)d_in[8];
  const float* g2 = (const float*)d_in[9];
  const float* b2 = (const float*)d_in[10];
  const float* w3 = (const float*)d_in[11];
  const float* b3 = (const float*)d_in[12];
  const float* wq = (const float*)d_in[13];
  const float* bq = (const float*)d_in[14];
  const float* wv = (const float*)d_in[15];
  const float* bv = (const float*)d_in[16];
  const float* wo = (const float*)d_in[17];
  const float* bo = (const float*)d_in[18];
  const float* pos_enc = (const float*)d_in[19];

  int N = in_sizes[0] / 3;
  int M = in_sizes[2];
  int NB = (N + 1023) / 1024;  // <= 256
  int NBKT = (N + 255) >> 8;   // <= 512
  int Np = (N + 4) & ~3;
  int NB1C = (M + CH - 1) / CH;

  float* ws = (float*)d_ws;
  float* stats1 = ws;                                 // 8
  float* stats2 = ws + 8;                             // 256 (ends 264)
  __hip_bfloat16* pnb = (__hip_bfloat16*)(ws + 264);  // 32*128 bf16 (ends 2312)
  float* bqp = ws + 2312;                             // 128
  float* bvp = ws + 2440;                             // 128 (ends 2568)
  int* cnt = (int*)(ws + 4096);                       // Np
  int* poffs = cnt + Np;                              // Np (N+1 used)
  int* bsum = poffs + Np;                             // 512
  int* bbase = bsum + 512;                            // 512
  int* bcur = bbase + 512;                            // 512
  int* ccnt = bcur + 512;                             // 512
  int* sbase = ccnt + 512;                            // 520 (513 used)
  unsigned* recs = (unsigned*)(sbase + 520);          // recn (padded)
  size_t recn = ((size_t)M + 8 * (size_t)N + 7) & ~(size_t)7;
  unsigned* stg = recs + recn;                          // M
  __hip_bfloat16* qnb = (__hip_bfloat16*)(stg + M);     // N*128
  __hip_bfloat16* vb = qnb + (size_t)N * CIN;           // N*128
  __hip_bfloat16* wqT = vb + (size_t)N * CIN;
  __hip_bfloat16* wvT = wqT + CIN * CIN;
  __hip_bfloat16* woT = wvT + CIN * CIN;
  __hip_bfloat16* W3qT = woT + CIN * CIN;
  __hip_bfloat16* W3vT = W3qT + CIN * CIN;
  __hip_bfloat16* w3b = W3vT + CIN * CIN;
  float* partials1 = (float*)(w3b + CIN * CIN);  // NB1*8
  float* partials2 = partials1 + NB1 * 8;        // 2*NB2*128
  float* outf = (float*)d_out;

  hipMemsetAsync(ccnt, 0, NBKT_MAX * sizeof(int), stream);

  k_fuseA<<<384, 256, 0, stream>>>(points, w1, partials1, pos_enc, wq, wv, wo,
                                   w3, pnb, wqT, wvT, woT, w3b, q_idx, ccnt, N,
                                   M);
  k_fuseB<<<NB2 + 1, 256, 0, stream>>>(points, w1, g1, b1, w2, partials1,
                                       partials2, ccnt, sbase, bcur, N);
  k_fuseC<<<6 + NB1C, 256, 0, stream>>>(partials1, partials2, stats1, stats2,
                                        w3b, wqT, wvT, wq, wv, b3, bq, bv, W3qT,
                                        W3vT, bqp, bvp, q_idx, k_idx,
                                        kernel_idx, bcur, stg, M);
  k_bucket2a<<<NBKT, 256, 0, stream>>>(stg, sbase, cnt, N);
  k_scan1<<<NB, 256, 0, stream>>>(cnt, poffs, bsum, N);
  k_scan2<<<1, 256, 0, stream>>>(bsum, bbase, NB, poffs + N);
  k_scan3<<<NB, 256, 0, stream>>>(cnt, poffs, bbase, recs, N);
  k_qv_b2b<<<NBKT + (N + 31) / 32, 256, 0, stream>>>(
      stg, sbase, poffs, recs, NBKT, points, feats, w1, g1, b1, w2, g2, b2, wqT,
      wvT, W3qT, W3vT, bqp, bvp, stats1, stats2, qnb, vb, N);
  k_gather_out<<<(N + 31) / 32, 512, 0, stream>>>(recs, poffs, qnb, vb, pnb,
                                                  woT, bo, outf, N);
}